// Round 1
// baseline (3179.417 us; speedup 1.0000x reference)
//
#include <hip/hip_runtime.h>
#include <cstdint>
#include <cstdio>

typedef unsigned short u16;
typedef __attribute__((ext_vector_type(8))) short short8;   // 8 bf16 (4 VGPRs)
typedef __attribute__((ext_vector_type(4))) float f32x4;

#define DEVFN __device__ __forceinline__

DEVFN u16 f2bf(float f){ union{float f; unsigned u;} v; v.f=f; unsigned r = v.u + 0x7fffu + ((v.u>>16)&1u); return (u16)(r>>16); }
DEVFN float bf2f(u16 h){ union{unsigned u; float f;} v; v.u = ((unsigned)h)<<16; return v.f; }

// ---------------- problem constants ----------------
static constexpr int NTOK = 65536;   // H*W
static constexpr int C    = 512;
static constexpr int GSPLIT = 32;    // split-K slabs for Gram
static constexpr int GKLEN  = NTOK / GSPLIT;  // 2048 tokens per slab

// ---------------- workspace layout (bytes) ----------------
static constexpr size_t OFF_XB    = 0;                   // bf16 x  [n][c]      64 MiB
static constexpr size_t OFF_XBT   = 67108864;            // bf16 x^T [c][n]     64 MiB
static constexpr size_t OFF_VB    = 134217728;           // bf16 v_inp [n][c]   64 MiB
static constexpr size_t OFF_E1    = 201326592;           // bf16 e1 [n][c]      64 MiB
static constexpr size_t OFF_GPART = 268435456;           // fp32 [32][512][512] 32 MiB
static constexpr size_t OFF_G     = 301989888;           // fp32 [512][512]
static constexpr size_t OFF_TQ    = 303038464;           // fp32 [512][512]
static constexpr size_t OFF_TK    = 304087040;           // fp32 [512][512]
static constexpr size_t OFF_WVT   = 305135616;           // bf16 Wv^T [n][k]
static constexpr size_t OFF_W2T   = 305659904;           // bf16 W2^T [e][c1]
static constexpr size_t OFF_ASAR  = 306184192;           // fp32 conv3 out [2][65536]
static constexpr size_t OFF_SS    = 306708480;           // fp32 sar_sobel [2][65536]
static constexpr size_t OFF_BNP   = 307232768;           // fp32 scale[2], shift[2]
static constexpr size_t OFF_QN    = 307233024;           // fp32 [512]
static constexpr size_t OFF_KN    = 307235072;           // fp32 [512]
static constexpr size_t OFF_ATTN  = 307237120;           // fp32 [8][64][64]
static constexpr size_t WS_NEEDED = 307368192;
// aliases (lifetimes disjoint, stream-ordered): VMB = OFF_XB, GELU = OFF_XBT

// =====================================================================
// Big bf16 MFMA GEMM: C[M][512] = A[M][K] * B  with B stored as [N][K] (B^T).
// 128x128 tile, 4 waves in 2x2, each wave 64x64 = 4x4 MFMA 16x16x32 frags.
// MODE 0: write bf16 C.  MODE 1: write fp32 partial slab (Gram split-K, z=slab).
// MODE 2: write fp32 C + bias[col].
// =====================================================================
template<int MODE>
__global__ __launch_bounds__(256) void gemm_bt(
    const u16* __restrict__ A, int lda,
    const u16* __restrict__ B, int ldb,
    int klen,
    void* __restrict__ Cout,
    const float* __restrict__ bias)
{
  __shared__ uint4 smem[1024];  // A tile: [0..511] = 128x32 bf16; B tile: [512..1023]
  const int tid  = threadIdx.x;
  const int lane = tid & 63;
  const int wv   = tid >> 6;
  const int wm   = (wv >> 1) * 64;
  const int wn   = (wv & 1) * 64;
  const int m0   = blockIdx.x * 128;
  const int n0   = blockIdx.y * 128;
  const int kb   = blockIdx.z * klen;

  const int q0 = tid, q1 = tid + 256;
  const size_t arow0 = (size_t)(m0 + (q0 >> 2)) * lda + (q0 & 3) * 8;
  const size_t arow1 = (size_t)(m0 + (q1 >> 2)) * lda + (q1 & 3) * 8;
  const size_t brow0 = (size_t)(n0 + (q0 >> 2)) * ldb + (q0 & 3) * 8;
  const size_t brow1 = (size_t)(n0 + (q1 >> 2)) * ldb + (q1 & 3) * 8;

  f32x4 acc[4][4] = {};
  const char* lAc = (const char*)smem;
  const char* lBc = (const char*)(smem + 512);
  const int ko = (lane >> 4) * 16;   // byte offset of this lane's k-octet
  const int ma = lane & 15;

  for (int k0 = kb; k0 < kb + klen; k0 += 32) {
    uint4 a0 = *(const uint4*)&A[arow0 + k0];
    uint4 a1 = *(const uint4*)&A[arow1 + k0];
    uint4 b0 = *(const uint4*)&B[brow0 + k0];
    uint4 b1 = *(const uint4*)&B[brow1 + k0];
    __syncthreads();                      // previous iter's compute done
    smem[q0] = a0; smem[q1] = a1; smem[512 + q0] = b0; smem[512 + q1] = b1;
    __syncthreads();
    short8 af[4], bfr[4];
#pragma unroll
    for (int mt = 0; mt < 4; mt++)
      af[mt] = *(const short8*)(lAc + (wm + mt * 16 + ma) * 64 + ko);
#pragma unroll
    for (int nt = 0; nt < 4; nt++)
      bfr[nt] = *(const short8*)(lBc + (wn + nt * 16 + ma) * 64 + ko);
#pragma unroll
    for (int mt = 0; mt < 4; mt++)
#pragma unroll
      for (int nt = 0; nt < 4; nt++)
        acc[mt][nt] = __builtin_amdgcn_mfma_f32_16x16x32_bf16(af[mt], bfr[nt], acc[mt][nt], 0, 0, 0);
  }

  const int col = lane & 15;
  const int rq  = (lane >> 4) * 4;
  float* Cf = (float*)Cout;
  u16*   Ch = (u16*)Cout;
  if (MODE == 1) Cf += (size_t)blockIdx.z * 512 * 512;
#pragma unroll
  for (int mt = 0; mt < 4; mt++) {
#pragma unroll
    for (int nt = 0; nt < 4; nt++) {
      const int mbase = m0 + wm + mt * 16 + rq;
      const int nn    = n0 + wn + nt * 16 + col;
#pragma unroll
      for (int r = 0; r < 4; r++) {
        float vv = acc[mt][nt][r];
        size_t idx = (size_t)(mbase + r) * 512 + nn;
        if (MODE == 0)      Ch[idx] = f2bf(vv);
        else if (MODE == 1) Cf[idx] = vv;
        else                Cf[idx] = vv + bias[nn];
      }
    }
  }
}

// ---------------- x fp32 [n][512] -> bf16 xb [n][512] and xbT [512][n] ----------------
__global__ void k_cast_transpose(const float* __restrict__ x, u16* __restrict__ xb, u16* __restrict__ xbT)
{
  __shared__ u16 tile[64][72];
  const int t0 = blockIdx.x * 64, c0 = blockIdx.y * 64;
  const int tx = threadIdx.x & 15, ty = threadIdx.x >> 4;
#pragma unroll
  for (int p = 0; p < 4; p++) {
    int t = ty + p * 16;
    float4 v = *(const float4*)&x[(size_t)(t0 + t) * 512 + c0 + tx * 4];
    ushort4 u; u.x = f2bf(v.x); u.y = f2bf(v.y); u.z = f2bf(v.z); u.w = f2bf(v.w);
    *(ushort4*)&xb[(size_t)(t0 + t) * 512 + c0 + tx * 4] = u;
    tile[t][tx*4+0] = u.x; tile[t][tx*4+1] = u.y; tile[t][tx*4+2] = u.z; tile[t][tx*4+3] = u.w;
  }
  __syncthreads();
#pragma unroll
  for (int p = 0; p < 4; p++) {
    int c = ty + p * 16;
    ushort4 u;
    u.x = tile[tx*4+0][c]; u.y = tile[tx*4+1][c]; u.z = tile[tx*4+2][c]; u.w = tile[tx*4+3][c];
    *(ushort4*)&xbT[(size_t)(c0 + c) * 65536 + t0 + tx * 4] = u;
  }
}

// ---------------- W fp32 [512][512] -> bf16 W^T [512][512] ----------------
__global__ void k_transpose_w(const float* __restrict__ Wsrc, u16* __restrict__ WT)
{
  __shared__ u16 tile[64][72];
  const int k0 = blockIdx.x * 64, n0 = blockIdx.y * 64;
  const int tx = threadIdx.x & 15, ty = threadIdx.x >> 4;
#pragma unroll
  for (int p = 0; p < 4; p++) {
    int t = ty + p * 16;
    float4 v = *(const float4*)&Wsrc[(size_t)(k0 + t) * 512 + n0 + tx * 4];
    tile[t][tx*4+0] = f2bf(v.x); tile[t][tx*4+1] = f2bf(v.y);
    tile[t][tx*4+2] = f2bf(v.z); tile[t][tx*4+3] = f2bf(v.w);
  }
  __syncthreads();
#pragma unroll
  for (int p = 0; p < 4; p++) {
    int c = ty + p * 16;
    ushort4 u;
    u.x = tile[tx*4+0][c]; u.y = tile[tx*4+1][c]; u.z = tile[tx*4+2][c]; u.w = tile[tx*4+3][c];
    *(ushort4*)&WT[(size_t)(n0 + c) * 512 + k0 + tx * 4] = u;
  }
}

// ---------------- reduce Gram partials ----------------
__global__ void k_reduce_g(const float* __restrict__ part, float* __restrict__ G)
{
  const int i = blockIdx.x * 256 + threadIdx.x;   // 262144 elements
  float s = 0.f;
  for (int z = 0; z < GSPLIT; z++) s += part[(size_t)z * 262144 + i];
  G[i] = s;
}

// ---------------- Tq = G@Wq, Tk = G@Wk (fp32 tiled, z selects) ----------------
__global__ __launch_bounds__(256) void k_gw(const float* __restrict__ G,
    const float* __restrict__ Wq, const float* __restrict__ Wk,
    float* __restrict__ Tq, float* __restrict__ Tk)
{
  const float* Bm = blockIdx.z ? Wk : Wq;
  float* Cm = blockIdx.z ? Tk : Tq;
  __shared__ float As[64][68];
  __shared__ float Bs[64][68];
  const int i0 = blockIdx.x * 64, j0 = blockIdx.y * 64;
  const int tx = threadIdx.x & 15, ty = threadIdx.x >> 4;
  float acc[4][4] = {};
  for (int k0 = 0; k0 < 512; k0 += 64) {
    __syncthreads();
#pragma unroll
    for (int p = 0; p < 4; p++) {
      int r = ty + p * 16;
      float4 a = *(const float4*)&G [(size_t)(i0 + r) * 512 + k0 + tx * 4];
      float4 b = *(const float4*)&Bm[(size_t)(k0 + r) * 512 + j0 + tx * 4];
      *(float4*)&As[r][tx * 4] = a;
      *(float4*)&Bs[r][tx * 4] = b;
    }
    __syncthreads();
    for (int kk = 0; kk < 64; kk++) {
      float a0 = As[ty*4+0][kk], a1 = As[ty*4+1][kk], a2 = As[ty*4+2][kk], a3 = As[ty*4+3][kk];
      float4 bq = *(const float4*)&Bs[kk][tx * 4];
      acc[0][0] += a0*bq.x; acc[0][1] += a0*bq.y; acc[0][2] += a0*bq.z; acc[0][3] += a0*bq.w;
      acc[1][0] += a1*bq.x; acc[1][1] += a1*bq.y; acc[1][2] += a1*bq.z; acc[1][3] += a1*bq.w;
      acc[2][0] += a2*bq.x; acc[2][1] += a2*bq.y; acc[2][2] += a2*bq.z; acc[2][3] += a2*bq.w;
      acc[3][0] += a3*bq.x; acc[3][1] += a3*bq.y; acc[3][2] += a3*bq.z; acc[3][3] += a3*bq.w;
    }
  }
#pragma unroll
  for (int u = 0; u < 4; u++) {
    float4 o = make_float4(acc[u][0], acc[u][1], acc[u][2], acc[u][3]);
    *(float4*)&Cm[(size_t)(i0 + ty * 4 + u) * 512 + j0 + tx * 4] = o;
  }
}

// ---------------- norms: ||q_c|| = sqrt(Wq[:,c] . Tq[:,c]) (clamped) ----------------
__global__ void k_norms(const float* __restrict__ Wq, const float* __restrict__ Tq,
                        const float* __restrict__ Wk, const float* __restrict__ Tk,
                        float* __restrict__ qn, float* __restrict__ kn)
{
  const int gw = (blockIdx.x * 256 + threadIdx.x) >> 6;  // 0..1023
  const int lane = threadIdx.x & 63;
  const float* Wm = (gw < 512) ? Wq : Wk;
  const float* Tm = (gw < 512) ? Tq : Tk;
  const int c = gw & 511;
  float s = 0.f;
  for (int r = lane; r < 512; r += 64) s += Wm[(size_t)r * 512 + c] * Tm[(size_t)r * 512 + c];
  for (int off = 32; off > 0; off >>= 1) s += __shfl_down(s, off);
  if (lane == 0) {
    float n = sqrtf(fmaxf(s, 0.f));
    ((gw < 512) ? qn : kn)[c] = fmaxf(n, 1e-12f);
  }
}

// ---------------- per-head: S = Wk_h^T Tq_h, scale by norms, softmax -> attn ----------------
__global__ __launch_bounds__(256) void k_attn(const float* __restrict__ Wk, const float* __restrict__ Tq,
    const float* __restrict__ qn, const float* __restrict__ kn,
    const float* __restrict__ rescale, float* __restrict__ attn)
{
  const int h = blockIdx.x, hd = h * 64;
  __shared__ float Ks[64][68];
  __shared__ float Qs[64][68];
  __shared__ float Ss[64][65];
  const int tx = threadIdx.x & 15, ty = threadIdx.x >> 4;
  float acc[4][4] = {};
  for (int k0 = 0; k0 < 512; k0 += 64) {
    __syncthreads();
#pragma unroll
    for (int p = 0; p < 4; p++) {
      int r = ty + p * 16;
      float4 a = *(const float4*)&Wk[(size_t)(k0 + r) * 512 + hd + tx * 4];
      float4 b = *(const float4*)&Tq[(size_t)(k0 + r) * 512 + hd + tx * 4];
      *(float4*)&Ks[r][tx * 4] = a;
      *(float4*)&Qs[r][tx * 4] = b;
    }
    __syncthreads();
    for (int kk = 0; kk < 64; kk++) {
      float a0 = Ks[kk][ty*4+0], a1 = Ks[kk][ty*4+1], a2 = Ks[kk][ty*4+2], a3 = Ks[kk][ty*4+3];
      float4 bq = *(const float4*)&Qs[kk][tx * 4];
      acc[0][0] += a0*bq.x; acc[0][1] += a0*bq.y; acc[0][2] += a0*bq.z; acc[0][3] += a0*bq.w;
      acc[1][0] += a1*bq.x; acc[1][1] += a1*bq.y; acc[1][2] += a1*bq.z; acc[1][3] += a1*bq.w;
      acc[2][0] += a2*bq.x; acc[2][1] += a2*bq.y; acc[2][2] += a2*bq.z; acc[2][3] += a2*bq.w;
      acc[3][0] += a3*bq.x; acc[3][1] += a3*bq.y; acc[3][2] += a3*bq.z; acc[3][3] += a3*bq.w;
    }
  }
#pragma unroll
  for (int u = 0; u < 4; u++)
#pragma unroll
    for (int v = 0; v < 4; v++)
      Ss[ty * 4 + u][tx * 4 + v] = acc[u][v];
  __syncthreads();
  if (threadIdx.x < 64) {
    const int i = threadIdx.x;
    const float sci = rescale[h] / kn[hd + i];
    float mx = -1e30f;
    for (int j = 0; j < 64; j++) {
      float L = Ss[i][j] * sci / qn[hd + j];
      Ss[i][j] = L;
      mx = fmaxf(mx, L);
    }
    float sum = 0.f;
    for (int j = 0; j < 64; j++) { float e = __expf(Ss[i][j] - mx); Ss[i][j] = e; sum += e; }
    float inv = 1.f / sum;
    for (int j = 0; j < 64; j++) attn[(size_t)h * 4096 + i * 64 + j] = Ss[i][j] * inv;
  }
}

// ---------------- fold attn into Wp: W2T[e][hd+j] = sum_i attn[h,i,j]*Wp[hd+i][e] ----------------
__global__ void k_w2t(const float* __restrict__ attn, const float* __restrict__ Wp, u16* __restrict__ W2T)
{
  const int h = blockIdx.x >> 3, e0 = (blockIdx.x & 7) * 64;
  __shared__ float As[64][65];
  for (int p = 0; p < 16; p++) {
    int idx = p * 256 + threadIdx.x;
    As[idx >> 6][idx & 63] = attn[(size_t)h * 4096 + idx];
  }
  __syncthreads();
  const int e = e0 + (threadIdx.x & 63);
  const int j4 = threadIdx.x >> 6;
  float s[16];
#pragma unroll
  for (int jj = 0; jj < 16; jj++) s[jj] = 0.f;
  for (int i = 0; i < 64; i++) {
    float wv_ = Wp[(size_t)(h * 64 + i) * 512 + e];
#pragma unroll
    for (int jj = 0; jj < 16; jj++) s[jj] += As[i][j4 * 16 + jj] * wv_;
  }
#pragma unroll
  for (int jj = 0; jj < 16; jj++)
    W2T[(size_t)e * 512 + h * 64 + j4 * 16 + jj] = f2bf(s[jj]);
}

// ---------------- SAR branch ----------------
__global__ void k_conv3(const float* __restrict__ sar, const float* __restrict__ w3,
                        const float* __restrict__ b3, float* __restrict__ a)
{
  const int oc = blockIdx.y;
  const int p = blockIdx.x * 256 + threadIdx.x;
  const int y = p >> 8, x = p & 255;
  float s = b3[oc];
#pragma unroll
  for (int ic = 0; ic < 2; ic++) {
    const float* img = sar + ic * 65536;
    const float* w = w3 + oc * 18 + ic * 9;
#pragma unroll
    for (int k = 0; k < 9; k++) {
      int yy = y + k / 3 - 1, xx = x + k % 3 - 1;
      if ((unsigned)yy < 256u && (unsigned)xx < 256u) s += w[k] * img[yy * 256 + xx];
    }
  }
  a[oc * 65536 + p] = s;
}

__global__ void k_bnstats(const float* __restrict__ a, const float* __restrict__ g,
                          const float* __restrict__ b, float* __restrict__ bnp)
{
  const int ch = blockIdx.x;
  const int tid = threadIdx.x;
  const float* src = a + ch * 65536;
  float s = 0.f, sq = 0.f;
  for (int i = tid; i < 65536; i += 256) { float v = src[i]; s += v; sq += v * v; }
  __shared__ float rs[256], rq[256];
  rs[tid] = s; rq[tid] = sq;
  __syncthreads();
  for (int o = 128; o > 0; o >>= 1) {
    if (tid < o) { rs[tid] += rs[tid + o]; rq[tid] += rq[tid + o]; }
    __syncthreads();
  }
  if (tid == 0) {
    float mu = rs[0] * (1.f / 65536.f);
    float var = rq[0] * (1.f / 65536.f) - mu * mu;
    float scale = g[ch] / sqrtf(var + 1e-5f);
    bnp[ch] = scale;
    bnp[2 + ch] = b[ch] - mu * scale;
  }
}

__global__ void k_sar2(const float* __restrict__ a, const float* __restrict__ bnp,
                       const float* __restrict__ sb, float* __restrict__ ss)
{
  const int p = blockIdx.x * 256 + threadIdx.x;
  const int y = p >> 8, x = p & 255;
  const float sc0 = bnp[0], sc1 = bnp[1], sh0 = bnp[2], sh1 = bnp[3];
  float bs[9];
  float bn0c = 0.f, bn1c = 0.f;
#pragma unroll
  for (int k = 0; k < 9; k++) {
    int yy = y + k / 3 - 1, xx = x + k % 3 - 1;
    float v0 = 0.f, v1 = 0.f;
    if ((unsigned)yy < 256u && (unsigned)xx < 256u) {
      int q = yy * 256 + xx;
      v0 = a[q] * sc0 + sh0;
      v1 = a[65536 + q] * sc1 + sh1;
    }
    bs[k] = v0 + v1;
    if (k == 4) { bn0c = v0; bn1c = v1; }
  }
  float gv = (bs[6] + 2.f * bs[7] + bs[8]) - (bs[0] + 2.f * bs[1] + bs[2]);
  float gh = (bs[2] + 2.f * bs[5] + bs[8]) - (bs[0] + 2.f * bs[3] + bs[6]);
  float s0 = gv + sb[0], s1 = gh + sb[1], s2 = gv + sb[2], s3 = gh + sb[3];
  ss[p]        = sqrtf(s0 * s0 + s1 * s1) + bn0c;
  ss[65536 + p] = sqrtf(s2 * s2 + s3 * s3) + bn1c;
}

// ---------------- e1 = 1x1 conv (2->512), NHWC bf16 ----------------
__global__ void k_e1(const float* __restrict__ ss, const float* __restrict__ w2,
                     const float* __restrict__ b2, u16* __restrict__ e1)
{
  const int gi = blockIdx.x * 256 + threadIdx.x;
  const int t = gi >> 7, c0 = (gi & 127) << 2;
  const float s0v = ss[t], s1v = ss[65536 + t];
  ushort4 o;
  o.x = f2bf(w2[(c0 + 0) * 2] * s0v + w2[(c0 + 0) * 2 + 1] * s1v + b2[c0 + 0]);
  o.y = f2bf(w2[(c0 + 1) * 2] * s0v + w2[(c0 + 1) * 2 + 1] * s1v + b2[c0 + 1]);
  o.z = f2bf(w2[(c0 + 2) * 2] * s0v + w2[(c0 + 2) * 2 + 1] * s1v + b2[c0 + 2]);
  o.w = f2bf(w2[(c0 + 3) * 2] * s0v + w2[(c0 + 3) * 2 + 1] * s1v + b2[c0 + 3]);
  *(ushort4*)&e1[(size_t)t * 512 + c0] = o;
}

// ---------------- mask = e1 + sigmoid(conv32(ss)) + depthwise5x5(e1); vm = v*mask ----------------
__global__ __launch_bounds__(256) void k_mask(const u16* __restrict__ e1, const float* __restrict__ ss,
    const float* __restrict__ w32, const float* __restrict__ b32,
    const float* __restrict__ dw, const float* __restrict__ db,
    const u16* __restrict__ vb, u16* __restrict__ vm)
{
  const int gi = blockIdx.x * 256 + threadIdx.x;
  const int t = gi >> 7, c0 = (gi & 127) << 2;
  const int y = t >> 8, x = t & 255;
  float n0[9], n1[9];
#pragma unroll
  for (int k = 0; k < 9; k++) {
    int yy = y + k / 3 - 1, xx = x + k % 3 - 1;
    bool in = (unsigned)yy < 256u && (unsigned)xx < 256u;
    int p = yy * 256 + xx;
    n0[k] = in ? ss[p] : 0.f;
    n1[k] = in ? ss[65536 + p] : 0.f;
  }
  float msk[4];
#pragma unroll
  for (int cc = 0; cc < 4; cc++) {
    int c = c0 + cc;
    const float* w = w32 + c * 18;
    float s = b32[c];
#pragma unroll
    for (int k = 0; k < 9; k++) s += w[k] * n0[k] + w[9 + k] * n1[k];
    msk[cc] = 1.f / (1.f + __expf(-s)) + db[c];   // e2 + depthwise bias
  }
#pragma unroll
  for (int dy = -2; dy <= 2; dy++)
#pragma unroll
    for (int dx = -2; dx <= 2; dx++) {
      int yy = y + dy, xx = x + dx;
      if ((unsigned)yy < 256u && (unsigned)xx < 256u) {
        ushort4 ev = *(const ushort4*)&e1[(size_t)((yy << 8) + xx) * 512 + c0];
        int off = (dy + 2) * 5 + dx + 2;
        msk[0] += bf2f(ev.x) * dw[(c0 + 0) * 25 + off];
        msk[1] += bf2f(ev.y) * dw[(c0 + 1) * 25 + off];
        msk[2] += bf2f(ev.z) * dw[(c0 + 2) * 25 + off];
        msk[3] += bf2f(ev.w) * dw[(c0 + 3) * 25 + off];
      }
    }
  ushort4 ec = *(const ushort4*)&e1[(size_t)t * 512 + c0];
  msk[0] += bf2f(ec.x); msk[1] += bf2f(ec.y); msk[2] += bf2f(ec.z); msk[3] += bf2f(ec.w);
  ushort4 vv = *(const ushort4*)&vb[(size_t)t * 512 + c0];
  ushort4 o;
  o.x = f2bf(bf2f(vv.x) * msk[0]);
  o.y = f2bf(bf2f(vv.y) * msk[1]);
  o.z = f2bf(bf2f(vv.z) * msk[2]);
  o.w = f2bf(bf2f(vv.w) * msk[3]);
  *(ushort4*)&vm[(size_t)t * 512 + c0] = o;
}

// ---------------- positional branch: depthwise3x3 -> exact GELU -> bf16 ----------------
__global__ void k_pe1(const u16* __restrict__ v, const float* __restrict__ w, u16* __restrict__ g)
{
  const int gi = blockIdx.x * 256 + threadIdx.x;
  const int t = gi >> 7, c0 = (gi & 127) << 2;
  const int y = t >> 8, x = t & 255;
  float s[4] = {0.f, 0.f, 0.f, 0.f};
#pragma unroll
  for (int k = 0; k < 9; k++) {
    int yy = y + k / 3 - 1, xx = x + k % 3 - 1;
    if ((unsigned)yy < 256u && (unsigned)xx < 256u) {
      ushort4 ev = *(const ushort4*)&v[(size_t)((yy << 8) + xx) * 512 + c0];
      s[0] += bf2f(ev.x) * w[(c0 + 0) * 9 + k];
      s[1] += bf2f(ev.y) * w[(c0 + 1) * 9 + k];
      s[2] += bf2f(ev.z) * w[(c0 + 2) * 9 + k];
      s[3] += bf2f(ev.w) * w[(c0 + 3) * 9 + k];
    }
  }
  ushort4 o;
#pragma unroll
  for (int cc = 0; cc < 4; cc++)
    s[cc] = 0.5f * s[cc] * (1.f + erff(s[cc] * 0.70710678118654752f));
  o.x = f2bf(s[0]); o.y = f2bf(s[1]); o.z = f2bf(s[2]); o.w = f2bf(s[3]);
  *(ushort4*)&g[(size_t)t * 512 + c0] = o;
}

// ---------------- second depthwise conv + add into out ----------------
__global__ void k_pe2_add(const u16* __restrict__ g, const float* __restrict__ w, float* __restrict__ out)
{
  const int gi = blockIdx.x * 256 + threadIdx.x;
  const int t = gi >> 7, c0 = (gi & 127) << 2;
  const int y = t >> 8, x = t & 255;
  float s[4] = {0.f, 0.f, 0.f, 0.f};
#pragma unroll
  for (int k = 0; k < 9; k++) {
    int yy = y + k / 3 - 1, xx = x + k % 3 - 1;
    if ((unsigned)yy < 256u && (unsigned)xx < 256u) {
      ushort4 ev = *(const ushort4*)&g[(size_t)((yy << 8) + xx) * 512 + c0];
      s[0] += bf2f(ev.x) * w[(c0 + 0) * 9 + k];
      s[1] += bf2f(ev.y) * w[(c0 + 1) * 9 + k];
      s[2] += bf2f(ev.z) * w[(c0 + 2) * 9 + k];
      s[3] += bf2f(ev.w) * w[(c0 + 3) * 9 + k];
    }
  }
  float4 o4 = *(float4*)&out[(size_t)t * 512 + c0];
  o4.x += s[0]; o4.y += s[1]; o4.z += s[2]; o4.w += s[3];
  *(float4*)&out[(size_t)t * 512 + c0] = o4;
}

// =====================================================================
extern "C" void kernel_launch(void* const* d_in, const int* in_sizes, int n_in,
                              void* d_out, int out_size, void* d_ws, size_t ws_size,
                              hipStream_t stream)
{
  (void)in_sizes; (void)n_in; (void)out_size;
  const float* x    = (const float*)d_in[0];
  const float* sar  = (const float*)d_in[1];
  const float* Wq   = (const float*)d_in[2];
  const float* Wk   = (const float*)d_in[3];
  const float* Wv   = (const float*)d_in[4];
  const float* resc = (const float*)d_in[5];
  const float* Wp   = (const float*)d_in[6];
  const float* bp   = (const float*)d_in[7];
  const float* pe1w = (const float*)d_in[8];
  const float* pe2w = (const float*)d_in[9];
  const float* w3   = (const float*)d_in[10];
  const float* b3   = (const float*)d_in[11];
  const float* bng  = (const float*)d_in[12];
  const float* bnb  = (const float*)d_in[13];
  const float* sb   = (const float*)d_in[14];
  const float* w2c  = (const float*)d_in[15];
  const float* b2c  = (const float*)d_in[16];
  const float* w32  = (const float*)d_in[17];
  const float* b32  = (const float*)d_in[18];
  const float* dw   = (const float*)d_in[19];
  const float* db   = (const float*)d_in[20];
  float* out = (float*)d_out;

  if (ws_size < WS_NEEDED)
    fprintf(stderr, "MS_MSA: workspace too small: have %zu need %zu\n", ws_size, WS_NEEDED);

  char* ws = (char*)d_ws;
  u16* XB    = (u16*)(ws + OFF_XB);
  u16* XBT   = (u16*)(ws + OFF_XBT);
  u16* VB    = (u16*)(ws + OFF_VB);
  u16* E1    = (u16*)(ws + OFF_E1);
  float* GPART = (float*)(ws + OFF_GPART);
  float* G     = (float*)(ws + OFF_G);
  float* TQ    = (float*)(ws + OFF_TQ);
  float* TK    = (float*)(ws + OFF_TK);
  u16* WVT   = (u16*)(ws + OFF_WVT);
  u16* W2T   = (u16*)(ws + OFF_W2T);
  float* ASAR = (float*)(ws + OFF_ASAR);
  float* SS   = (float*)(ws + OFF_SS);
  float* BNP  = (float*)(ws + OFF_BNP);
  float* QN   = (float*)(ws + OFF_QN);
  float* KN   = (float*)(ws + OFF_KN);
  float* ATTN = (float*)(ws + OFF_ATTN);
  u16* VMB  = XB;    // alias: xb dead after gemm_v
  u16* GELU = XBT;   // alias: xbT dead after Gram

  // --- x -> bf16 (row + transposed) ---
  k_cast_transpose<<<dim3(1024, 8), 256, 0, stream>>>(x, XB, XBT);
  // --- G = X^T X (split-K partials + reduce) ---
  gemm_bt<1><<<dim3(4, 4, GSPLIT), 256, 0, stream>>>(XBT, NTOK, XBT, NTOK, GKLEN, GPART, nullptr);
  k_reduce_g<<<1024, 256, 0, stream>>>(GPART, G);
  // --- v_inp = x @ Wv (bf16 out) ---
  k_transpose_w<<<dim3(8, 8), 256, 0, stream>>>(Wv, WVT);
  gemm_bt<0><<<dim3(512, 4), 256, 0, stream>>>(XB, 512, WVT, 512, 512, VB, nullptr);
  // --- attention statistics from G ---
  k_gw<<<dim3(8, 8, 2), 256, 0, stream>>>(G, Wq, Wk, TQ, TK);
  k_norms<<<256, 256, 0, stream>>>(Wq, TQ, Wk, TK, QN, KN);
  k_attn<<<8, 256, 0, stream>>>(Wk, TQ, QN, KN, resc, ATTN);
  k_w2t<<<64, 256, 0, stream>>>(ATTN, Wp, W2T);
  // --- SAR mask branch ---
  k_conv3<<<dim3(256, 2), 256, 0, stream>>>(sar, w3, b3, ASAR);
  k_bnstats<<<2, 256, 0, stream>>>(ASAR, bng, bnb, BNP);
  k_sar2<<<256, 256, 0, stream>>>(ASAR, BNP, sb, SS);
  k_e1<<<32768, 256, 0, stream>>>(SS, w2c, b2c, E1);
  k_mask<<<32768, 256, 0, stream>>>(E1, SS, w32, b32, dw, db, VB, VMB);
  // --- positional branch stage 1 ---
  k_pe1<<<32768, 256, 0, stream>>>(VB, pe1w, GELU);
  // --- out = vm @ W2 + bp, then += pe2 conv ---
  gemm_bt<2><<<dim3(512, 4), 256, 0, stream>>>(VMB, 512, W2T, 512, 512, out, bp);
  k_pe2_add<<<32768, 256, 0, stream>>>(GELU, pe2w, out);
}

// Round 2
// 1212.017 us; speedup vs baseline: 2.6232x; 2.6232x over previous
//
#include <hip/hip_runtime.h>
#include <cstdint>
#include <cstdio>

typedef unsigned short u16;
typedef __attribute__((ext_vector_type(8))) short short8;   // 8 bf16 (4 VGPRs)
typedef __attribute__((ext_vector_type(4))) float f32x4;

#define DEVFN __device__ __forceinline__

DEVFN u16 f2bf(float f){ union{float f; unsigned u;} v; v.f=f; unsigned r = v.u + 0x7fffu + ((v.u>>16)&1u); return (u16)(r>>16); }
DEVFN float bf2f(u16 h){ union{unsigned u; float f;} v; v.u = ((unsigned)h)<<16; return v.f; }

// async global->LDS, 16B per lane (dwordx4). LDS dest must be wave-uniform base + lane*16.
#define GLOAD_LDS16(gp, lp) __builtin_amdgcn_global_load_lds( \
    (const __attribute__((address_space(1))) void*)(gp), \
    (__attribute__((address_space(3))) void*)(lp), 16, 0, 0)

// ---------------- problem constants ----------------
static constexpr int NTOK = 65536;   // H*W
static constexpr int GSPLIT = 32;    // split-K slabs for Gram
static constexpr int GKLEN  = NTOK / GSPLIT;

// ---------------- workspace layout (bytes) ----------------
static constexpr size_t MB = 1024 * 1024;
static constexpr size_t OFF_XB    = 0;          // bf16 x  [n][c]    64 MiB   (alias: VMT)
static constexpr size_t OFF_XBT   = 64 * MB;    // bf16 x^T [c][n]   64 MiB   (alias: GT)
static constexpr size_t OFF_VB    = 128 * MB;   // bf16 v_inp [n][c] 64 MiB   (alias: VM)
static constexpr size_t OFF_VT    = 192 * MB;   // bf16 v^T [c][n]   64 MiB
static constexpr size_t OFF_GPART = 256 * MB;   // fp32 [32][512][512] 32 MiB
static constexpr size_t OFF_G     = 288 * MB;
static constexpr size_t OFF_TQ    = 289 * MB;
static constexpr size_t OFF_TK    = 290 * MB;
static constexpr size_t OFF_WVT   = 291 * MB;            // bf16 Wv^T
static constexpr size_t OFF_W2T   = 291 * MB + 524288;   // bf16 W2^T
static constexpr size_t OFF_ASAR  = 292 * MB;            // fp32 [2][65536]
static constexpr size_t OFF_SS    = 292 * MB + 524288;   // fp32 [2][65536]
static constexpr size_t OFF_BNP   = 293 * MB;
static constexpr size_t OFF_QN    = 293 * MB + 4096;
static constexpr size_t OFF_KN    = 293 * MB + 8192;
static constexpr size_t OFF_ATTN  = 293 * MB + 12288;    // fp32 [8][64][64]
static constexpr size_t WS_NEEDED = 294 * MB;

// =====================================================================
// bf16 MFMA GEMM: C[M][512] = A[M][K] * B with B stored as [N][K] (B^T).
// 128x128 tile, 4 waves 2x2, wave = 64x64 via 4x4 16x16x32 frags.
// Staging via global_load_lds width=16 (m97 pattern).
// MODE 0: bf16 C. MODE 1: fp32 partial slab (split-K, z). MODE 2: fp32 C + bias.
// =====================================================================
template<int MODE>
__global__ __launch_bounds__(256) void gemm_bt(
    const u16* __restrict__ A, int lda,
    const u16* __restrict__ B, int ldb,
    int klen,
    void* __restrict__ Cout,
    const float* __restrict__ bias)
{
  __shared__ uint4 smem[1024];  // A tile [0..511] = 128x32 bf16 (64B rows); B tile [512..1023]
  const int tid  = threadIdx.x;
  const int lane = tid & 63;
  const int wv   = tid >> 6;
  const int wm   = (wv >> 1) * 64;
  const int wn   = (wv & 1) * 64;
  const int m0   = blockIdx.x * 128;
  const int n0   = blockIdx.y * 128;
  const int kb   = blockIdx.z * klen;

  const int q0 = tid, q1 = tid + 256;
  const size_t arow0 = (size_t)(m0 + (q0 >> 2)) * lda + (q0 & 3) * 8;
  const size_t arow1 = (size_t)(m0 + (q1 >> 2)) * lda + (q1 & 3) * 8;
  const size_t brow0 = (size_t)(n0 + (q0 >> 2)) * ldb + (q0 & 3) * 8;
  const size_t brow1 = (size_t)(n0 + (q1 >> 2)) * ldb + (q1 & 3) * 8;

  f32x4 acc[4][4] = {};
  const char* lAc = (const char*)smem;
  const char* lBc = (const char*)(smem + 512);
  const int ko = (lane >> 4) * 16;
  const int ma = lane & 15;

  for (int k0 = kb; k0 < kb + klen; k0 += 32) {
    __syncthreads();                      // all waves done reading previous tile
    GLOAD_LDS16(&A[arow0 + k0], &smem[q0]);
    GLOAD_LDS16(&A[arow1 + k0], &smem[q1]);
    GLOAD_LDS16(&B[brow0 + k0], &smem[512 + q0]);
    GLOAD_LDS16(&B[brow1 + k0], &smem[512 + q1]);
    __syncthreads();                      // drains vmcnt -> LDS data visible
    short8 af[4], bfr[4];
#pragma unroll
    for (int mt = 0; mt < 4; mt++)
      af[mt] = *(const short8*)(lAc + (wm + mt * 16 + ma) * 64 + ko);
#pragma unroll
    for (int nt = 0; nt < 4; nt++)
      bfr[nt] = *(const short8*)(lBc + (wn + nt * 16 + ma) * 64 + ko);
#pragma unroll
    for (int mt = 0; mt < 4; mt++)
#pragma unroll
      for (int nt = 0; nt < 4; nt++)
        acc[mt][nt] = __builtin_amdgcn_mfma_f32_16x16x32_bf16(af[mt], bfr[nt], acc[mt][nt], 0, 0, 0);
  }

  const int col = lane & 15;
  const int rq  = (lane >> 4) * 4;
  float* Cf = (float*)Cout;
  u16*   Ch = (u16*)Cout;
  if (MODE == 1) Cf += (size_t)blockIdx.z * 512 * 512;
#pragma unroll
  for (int mt = 0; mt < 4; mt++) {
#pragma unroll
    for (int nt = 0; nt < 4; nt++) {
      const int mbase = m0 + wm + mt * 16 + rq;
      const int nn    = n0 + wn + nt * 16 + col;
#pragma unroll
      for (int r = 0; r < 4; r++) {
        float vv = acc[mt][nt][r];
        size_t idx = (size_t)(mbase + r) * 512 + nn;
        if (MODE == 0)      Ch[idx] = f2bf(vv);
        else if (MODE == 1) Cf[idx] = vv;
        else                Cf[idx] = vv + bias[nn];
      }
    }
  }
}

// ---------------- x fp32 [n][512] -> bf16 xb [n][512] and xbT [512][n] ----------------
__global__ void k_cast_transpose(const float* __restrict__ x, u16* __restrict__ xb, u16* __restrict__ xbT)
{
  __shared__ u16 tile[64][72];
  const int t0 = blockIdx.x * 64, c0 = blockIdx.y * 64;
  const int tx = threadIdx.x & 15, ty = threadIdx.x >> 4;
#pragma unroll
  for (int p = 0; p < 4; p++) {
    int t = ty + p * 16;
    float4 v = *(const float4*)&x[(size_t)(t0 + t) * 512 + c0 + tx * 4];
    ushort4 u; u.x = f2bf(v.x); u.y = f2bf(v.y); u.z = f2bf(v.z); u.w = f2bf(v.w);
    *(ushort4*)&xb[(size_t)(t0 + t) * 512 + c0 + tx * 4] = u;
    tile[t][tx*4+0] = u.x; tile[t][tx*4+1] = u.y; tile[t][tx*4+2] = u.z; tile[t][tx*4+3] = u.w;
  }
  __syncthreads();
#pragma unroll
  for (int p = 0; p < 4; p++) {
    int c = ty + p * 16;
    ushort4 u;
    u.x = tile[tx*4+0][c]; u.y = tile[tx*4+1][c]; u.z = tile[tx*4+2][c]; u.w = tile[tx*4+3][c];
    *(ushort4*)&xbT[(size_t)(c0 + c) * 65536 + t0 + tx * 4] = u;
  }
}

// ---------------- generic bf16 tiled transpose: src[srows][scols] -> dst[scols][srows] ----------------
__global__ void k_tbf16(const u16* __restrict__ src, u16* __restrict__ dst, int srows, int scols)
{
  __shared__ u16 tile[64][72];
  const int r0 = blockIdx.x * 64, c0v = blockIdx.y * 64;
  const int tx = threadIdx.x & 15, ty = threadIdx.x >> 4;
#pragma unroll
  for (int p = 0; p < 4; p++) {
    int r = ty + p * 16;
    ushort4 u = *(const ushort4*)&src[(size_t)(r0 + r) * scols + c0v + tx * 4];
    tile[r][tx*4+0] = u.x; tile[r][tx*4+1] = u.y; tile[r][tx*4+2] = u.z; tile[r][tx*4+3] = u.w;
  }
  __syncthreads();
#pragma unroll
  for (int p = 0; p < 4; p++) {
    int c = ty + p * 16;
    ushort4 u;
    u.x = tile[tx*4+0][c]; u.y = tile[tx*4+1][c]; u.z = tile[tx*4+2][c]; u.w = tile[tx*4+3][c];
    *(ushort4*)&dst[(size_t)(c0v + c) * srows + r0 + tx * 4] = u;
  }
}

// ---------------- W fp32 [512][512] -> bf16 W^T ----------------
__global__ void k_transpose_w(const float* __restrict__ Wsrc, u16* __restrict__ WT)
{
  __shared__ u16 tile[64][72];
  const int k0 = blockIdx.x * 64, n0 = blockIdx.y * 64;
  const int tx = threadIdx.x & 15, ty = threadIdx.x >> 4;
#pragma unroll
  for (int p = 0; p < 4; p++) {
    int t = ty + p * 16;
    float4 v = *(const float4*)&Wsrc[(size_t)(k0 + t) * 512 + n0 + tx * 4];
    tile[t][tx*4+0] = f2bf(v.x); tile[t][tx*4+1] = f2bf(v.y);
    tile[t][tx*4+2] = f2bf(v.z); tile[t][tx*4+3] = f2bf(v.w);
  }
  __syncthreads();
#pragma unroll
  for (int p = 0; p < 4; p++) {
    int c = ty + p * 16;
    ushort4 u;
    u.x = tile[tx*4+0][c]; u.y = tile[tx*4+1][c]; u.z = tile[tx*4+2][c]; u.w = tile[tx*4+3][c];
    *(ushort4*)&WT[(size_t)(n0 + c) * 512 + k0 + tx * 4] = u;
  }
}

// ---------------- reduce Gram partials ----------------
__global__ void k_reduce_g(const float* __restrict__ part, float* __restrict__ G)
{
  const int i = blockIdx.x * 256 + threadIdx.x;
  float s = 0.f;
  for (int z = 0; z < GSPLIT; z++) s += part[(size_t)z * 262144 + i];
  G[i] = s;
}

// ---------------- Tq = G@Wq, Tk = G@Wk ----------------
__global__ __launch_bounds__(256) void k_gw(const float* __restrict__ G,
    const float* __restrict__ Wq, const float* __restrict__ Wk,
    float* __restrict__ Tq, float* __restrict__ Tk)
{
  const float* Bm = blockIdx.z ? Wk : Wq;
  float* Cm = blockIdx.z ? Tk : Tq;
  __shared__ float As[64][68];
  __shared__ float Bs[64][68];
  const int i0 = blockIdx.x * 64, j0 = blockIdx.y * 64;
  const int tx = threadIdx.x & 15, ty = threadIdx.x >> 4;
  float acc[4][4] = {};
  for (int k0 = 0; k0 < 512; k0 += 64) {
    __syncthreads();
#pragma unroll
    for (int p = 0; p < 4; p++) {
      int r = ty + p * 16;
      float4 a = *(const float4*)&G [(size_t)(i0 + r) * 512 + k0 + tx * 4];
      float4 b = *(const float4*)&Bm[(size_t)(k0 + r) * 512 + j0 + tx * 4];
      *(float4*)&As[r][tx * 4] = a;
      *(float4*)&Bs[r][tx * 4] = b;
    }
    __syncthreads();
    for (int kk = 0; kk < 64; kk++) {
      float a0 = As[ty*4+0][kk], a1 = As[ty*4+1][kk], a2 = As[ty*4+2][kk], a3 = As[ty*4+3][kk];
      float4 bq = *(const float4*)&Bs[kk][tx * 4];
      acc[0][0] += a0*bq.x; acc[0][1] += a0*bq.y; acc[0][2] += a0*bq.z; acc[0][3] += a0*bq.w;
      acc[1][0] += a1*bq.x; acc[1][1] += a1*bq.y; acc[1][2] += a1*bq.z; acc[1][3] += a1*bq.w;
      acc[2][0] += a2*bq.x; acc[2][1] += a2*bq.y; acc[2][2] += a2*bq.z; acc[2][3] += a2*bq.w;
      acc[3][0] += a3*bq.x; acc[3][1] += a3*bq.y; acc[3][2] += a3*bq.z; acc[3][3] += a3*bq.w;
    }
  }
#pragma unroll
  for (int u = 0; u < 4; u++) {
    float4 o = make_float4(acc[u][0], acc[u][1], acc[u][2], acc[u][3]);
    *(float4*)&Cm[(size_t)(i0 + ty * 4 + u) * 512 + j0 + tx * 4] = o;
  }
}

// ---------------- norms ----------------
__global__ void k_norms(const float* __restrict__ Wq, const float* __restrict__ Tq,
                        const float* __restrict__ Wk, const float* __restrict__ Tk,
                        float* __restrict__ qn, float* __restrict__ kn)
{
  const int gw = (blockIdx.x * 256 + threadIdx.x) >> 6;
  const int lane = threadIdx.x & 63;
  const float* Wm = (gw < 512) ? Wq : Wk;
  const float* Tm = (gw < 512) ? Tq : Tk;
  const int c = gw & 511;
  float s = 0.f;
  for (int r = lane; r < 512; r += 64) s += Wm[(size_t)r * 512 + c] * Tm[(size_t)r * 512 + c];
  for (int off = 32; off > 0; off >>= 1) s += __shfl_down(s, off);
  if (lane == 0) {
    float n = sqrtf(fmaxf(s, 0.f));
    ((gw < 512) ? qn : kn)[c] = fmaxf(n, 1e-12f);
  }
}

// ---------------- per-head logits + softmax ----------------
__global__ __launch_bounds__(256) void k_attn(const float* __restrict__ Wk, const float* __restrict__ Tq,
    const float* __restrict__ qn, const float* __restrict__ kn,
    const float* __restrict__ rescale, float* __restrict__ attn)
{
  const int h = blockIdx.x, hd = h * 64;
  __shared__ float Ks[64][68];
  __shared__ float Qs[64][68];
  __shared__ float Ss[64][65];
  const int tx = threadIdx.x & 15, ty = threadIdx.x >> 4;
  float acc[4][4] = {};
  for (int k0 = 0; k0 < 512; k0 += 64) {
    __syncthreads();
#pragma unroll
    for (int p = 0; p < 4; p++) {
      int r = ty + p * 16;
      float4 a = *(const float4*)&Wk[(size_t)(k0 + r) * 512 + hd + tx * 4];
      float4 b = *(const float4*)&Tq[(size_t)(k0 + r) * 512 + hd + tx * 4];
      *(float4*)&Ks[r][tx * 4] = a;
      *(float4*)&Qs[r][tx * 4] = b;
    }
    __syncthreads();
    for (int kk = 0; kk < 64; kk++) {
      float a0 = Ks[kk][ty*4+0], a1 = Ks[kk][ty*4+1], a2 = Ks[kk][ty*4+2], a3 = Ks[kk][ty*4+3];
      float4 bq = *(const float4*)&Qs[kk][tx * 4];
      acc[0][0] += a0*bq.x; acc[0][1] += a0*bq.y; acc[0][2] += a0*bq.z; acc[0][3] += a0*bq.w;
      acc[1][0] += a1*bq.x; acc[1][1] += a1*bq.y; acc[1][2] += a1*bq.z; acc[1][3] += a1*bq.w;
      acc[2][0] += a2*bq.x; acc[2][1] += a2*bq.y; acc[2][2] += a2*bq.z; acc[2][3] += a2*bq.w;
      acc[3][0] += a3*bq.x; acc[3][1] += a3*bq.y; acc[3][2] += a3*bq.z; acc[3][3] += a3*bq.w;
    }
  }
#pragma unroll
  for (int u = 0; u < 4; u++)
#pragma unroll
    for (int v = 0; v < 4; v++)
      Ss[ty * 4 + u][tx * 4 + v] = acc[u][v];
  __syncthreads();
  if (threadIdx.x < 64) {
    const int i = threadIdx.x;
    const float sci = rescale[h] / kn[hd + i];
    float mx = -1e30f;
    for (int j = 0; j < 64; j++) {
      float L = Ss[i][j] * sci / qn[hd + j];
      Ss[i][j] = L;
      mx = fmaxf(mx, L);
    }
    float sum = 0.f;
    for (int j = 0; j < 64; j++) { float e = __expf(Ss[i][j] - mx); Ss[i][j] = e; sum += e; }
    float inv = 1.f / sum;
    for (int j = 0; j < 64; j++) attn[(size_t)h * 4096 + i * 64 + j] = Ss[i][j] * inv;
  }
}

// ---------------- fold attn into Wp ----------------
__global__ void k_w2t(const float* __restrict__ attn, const float* __restrict__ Wp, u16* __restrict__ W2T)
{
  const int h = blockIdx.x >> 3, e0 = (blockIdx.x & 7) * 64;
  __shared__ float As[64][65];
  for (int p = 0; p < 16; p++) {
    int idx = p * 256 + threadIdx.x;
    As[idx >> 6][idx & 63] = attn[(size_t)h * 4096 + idx];
  }
  __syncthreads();
  const int e = e0 + (threadIdx.x & 63);
  const int j4 = threadIdx.x >> 6;
  float s[16];
#pragma unroll
  for (int jj = 0; jj < 16; jj++) s[jj] = 0.f;
  for (int i = 0; i < 64; i++) {
    float wv_ = Wp[(size_t)(h * 64 + i) * 512 + e];
#pragma unroll
    for (int jj = 0; jj < 16; jj++) s[jj] += As[i][j4 * 16 + jj] * wv_;
  }
#pragma unroll
  for (int jj = 0; jj < 16; jj++)
    W2T[(size_t)e * 512 + h * 64 + j4 * 16 + jj] = f2bf(s[jj]);
}

// ---------------- SAR branch ----------------
__global__ void k_conv3(const float* __restrict__ sar, const float* __restrict__ w3,
                        const float* __restrict__ b3, float* __restrict__ a)
{
  const int oc = blockIdx.y;
  const int p = blockIdx.x * 256 + threadIdx.x;
  const int y = p >> 8, x = p & 255;
  float s = b3[oc];
#pragma unroll
  for (int ic = 0; ic < 2; ic++) {
    const float* img = sar + ic * 65536;
    const float* w = w3 + oc * 18 + ic * 9;
#pragma unroll
    for (int k = 0; k < 9; k++) {
      int yy = y + k / 3 - 1, xx = x + k % 3 - 1;
      if ((unsigned)yy < 256u && (unsigned)xx < 256u) s += w[k] * img[yy * 256 + xx];
    }
  }
  a[oc * 65536 + p] = s;
}

__global__ void k_bnstats(const float* __restrict__ a, const float* __restrict__ g,
                          const float* __restrict__ b, float* __restrict__ bnp)
{
  const int ch = blockIdx.x;
  const int tid = threadIdx.x;
  const float* src = a + ch * 65536;
  float s = 0.f, sq = 0.f;
  for (int i = tid; i < 65536; i += 256) { float v = src[i]; s += v; sq += v * v; }
  __shared__ float rs[256], rq[256];
  rs[tid] = s; rq[tid] = sq;
  __syncthreads();
  for (int o = 128; o > 0; o >>= 1) {
    if (tid < o) { rs[tid] += rs[tid + o]; rq[tid] += rq[tid + o]; }
    __syncthreads();
  }
  if (tid == 0) {
    float mu = rs[0] * (1.f / 65536.f);
    float var = rq[0] * (1.f / 65536.f) - mu * mu;
    float scale = g[ch] / sqrtf(var + 1e-5f);
    bnp[ch] = scale;
    bnp[2 + ch] = b[ch] - mu * scale;
  }
}

__global__ void k_sar2(const float* __restrict__ a, const float* __restrict__ bnp,
                       const float* __restrict__ sb, float* __restrict__ ss)
{
  const int p = blockIdx.x * 256 + threadIdx.x;
  const int y = p >> 8, x = p & 255;
  const float sc0 = bnp[0], sc1 = bnp[1], sh0 = bnp[2], sh1 = bnp[3];
  float bs[9];
  float bn0c = 0.f, bn1c = 0.f;
#pragma unroll
  for (int k = 0; k < 9; k++) {
    int yy = y + k / 3 - 1, xx = x + k % 3 - 1;
    float v0 = 0.f, v1 = 0.f;
    if ((unsigned)yy < 256u && (unsigned)xx < 256u) {
      int q = yy * 256 + xx;
      v0 = a[q] * sc0 + sh0;
      v1 = a[65536 + q] * sc1 + sh1;
    }
    bs[k] = v0 + v1;
    if (k == 4) { bn0c = v0; bn1c = v1; }
  }
  float gv = (bs[6] + 2.f * bs[7] + bs[8]) - (bs[0] + 2.f * bs[1] + bs[2]);
  float gh = (bs[2] + 2.f * bs[5] + bs[8]) - (bs[0] + 2.f * bs[3] + bs[6]);
  float s0 = gv + sb[0], s1 = gh + sb[1], s2 = gv + sb[2], s3 = gh + sb[3];
  ss[p]         = sqrtf(s0 * s0 + s1 * s1) + bn0c;
  ss[65536 + p] = sqrtf(s2 * s2 + s3 * s3) + bn1c;
}

// =====================================================================
// k_mask2: mask = e1 + sigmoid(conv32(s)) + depthwise5x5(e1), vmt = vt * mask.
// Plane layout: block = 32x32 pixel tile x channel-quad (blockIdx.y).
// e1 = a*s0 + b*s1 + beta*iota  (rank-2 + indicator) -> dconv via u0,u1,ui.
// All weights wave-uniform -> scalar loads. s-windows staged in LDS.
// =====================================================================
__global__ __launch_bounds__(256) void k_mask2(
    const float* __restrict__ ss,
    const float* __restrict__ w2,  const float* __restrict__ b2,
    const float* __restrict__ w32, const float* __restrict__ b32,
    const float* __restrict__ dw,  const float* __restrict__ db,
    const u16* __restrict__ vt, u16* __restrict__ vmt)
{
  __shared__ __align__(16) float sw0[1296];  // 36x36 window of s0 (zero-padded)
  __shared__ __align__(16) float sw1[1296];
  __shared__ __align__(16) float swi[1296];  // in-bounds indicator
  const int bxx = blockIdx.x & 7, byy = blockIdx.x >> 3;
  const int tx0 = bxx * 32, ty0 = byy * 32;
  const int c0 = blockIdx.y * 4;
  const bool border = (bxx == 0) || (bxx == 7) || (byy == 0) || (byy == 7);

  for (int i = threadIdx.x; i < 1296; i += 256) {
    int r = i / 36, cl = i - r * 36;
    int gy = ty0 - 2 + r, gx = tx0 - 2 + cl;
    bool in = ((unsigned)gy < 256u) & ((unsigned)gx < 256u);
    int gp = gy * 256 + gx;
    sw0[i] = in ? ss[gp] : 0.f;
    sw1[i] = in ? ss[65536 + gp] : 0.f;
    swi[i] = in ? 1.f : 0.f;
  }
  __syncthreads();

  const int g = threadIdx.x & 7;      // x-group: 4 px each
  const int row = threadIdx.x >> 3;   // 0..31
  float u0[4][4] = {}, u1[4][4] = {}, ui[4][4] = {}, a32[4][4] = {};
  float s0c[4], s1c[4];

#pragma unroll
  for (int ky = 0; ky < 5; ky++) {
    const float* rp0 = &sw0[(row + ky) * 36 + g * 4];
    const float* rp1 = &sw1[(row + ky) * 36 + g * 4];
    float4 p0a = *(const float4*)rp0, p0b = *(const float4*)(rp0 + 4);
    float4 p1a = *(const float4*)rp1, p1b = *(const float4*)(rp1 + 4);
    float r0[8] = {p0a.x, p0a.y, p0a.z, p0a.w, p0b.x, p0b.y, p0b.z, p0b.w};
    float r1[8] = {p1a.x, p1a.y, p1a.z, p1a.w, p1b.x, p1b.y, p1b.z, p1b.w};
    if (ky == 2) {
#pragma unroll
      for (int j = 0; j < 4; j++) { s0c[j] = r0[j + 2]; s1c[j] = r1[j + 2]; }
    }
#pragma unroll
    for (int dx = 0; dx < 5; dx++) {
#pragma unroll
      for (int cc = 0; cc < 4; cc++) {
        float wdw = dw[(c0 + cc) * 25 + ky * 5 + dx];    // uniform -> s_load
#pragma unroll
        for (int j = 0; j < 4; j++) {
          u0[cc][j] += wdw * r0[dx + j];
          u1[cc][j] += wdw * r1[dx + j];
        }
      }
    }
    if (border) {
      const float* rpi = &swi[(row + ky) * 36 + g * 4];
      float4 pia = *(const float4*)rpi, pib = *(const float4*)(rpi + 4);
      float ri[8] = {pia.x, pia.y, pia.z, pia.w, pib.x, pib.y, pib.z, pib.w};
#pragma unroll
      for (int dx = 0; dx < 5; dx++)
#pragma unroll
        for (int cc = 0; cc < 4; cc++) {
          float wdw = dw[(c0 + cc) * 25 + ky * 5 + dx];
#pragma unroll
          for (int j = 0; j < 4; j++) ui[cc][j] += wdw * ri[dx + j];
        }
    }
    if (ky >= 1 && ky <= 3) {
#pragma unroll
      for (int dx = 0; dx < 3; dx++)
#pragma unroll
        for (int cc = 0; cc < 4; cc++) {
          float wa = w32[(c0 + cc) * 18 + (ky - 1) * 3 + dx];
          float wb = w32[(c0 + cc) * 18 + 9 + (ky - 1) * 3 + dx];
#pragma unroll
          for (int j = 0; j < 4; j++)
            a32[cc][j] += wa * r0[dx + 1 + j] + wb * r1[dx + 1 + j];
        }
    }
  }

  const int y = ty0 + row, xg = tx0 + g * 4;
#pragma unroll
  for (int cc = 0; cc < 4; cc++) {
    const int c = c0 + cc;
    const float a = w2[c * 2], b = w2[c * 2 + 1], beta = b2[c];
    const float bb = b32[c], dbv = db[c];
    float wsum = 0.f;
    if (!border) {
#pragma unroll
      for (int t = 0; t < 25; t++) wsum += dw[c * 25 + t];
    }
    ushort4 vv = *(const ushort4*)&vt[(size_t)c * 65536 + y * 256 + xg];
    float vf[4] = {bf2f(vv.x), bf2f(vv.y), bf2f(vv.z), bf2f(vv.w)};
    ushort4 o;
    u16 ov[4];
#pragma unroll
    for (int j = 0; j < 4; j++) {
      float W = border ? ui[cc][j] : wsum;
      float sig = 1.f / (1.f + __expf(-(a32[cc][j] + bb)));
      float m = a * (s0c[j] + u0[cc][j]) + b * (s1c[j] + u1[cc][j])
              + beta * (1.f + W) + sig + dbv;
      ov[j] = f2bf(vf[j] * m);
    }
    o.x = ov[0]; o.y = ov[1]; o.z = ov[2]; o.w = ov[3];
    *(ushort4*)&vmt[(size_t)c * 65536 + y * 256 + xg] = o;
  }
}

// ---------------- pe1: depthwise3x3 on VT plane -> exact GELU -> GT plane ----------------
__global__ __launch_bounds__(256) void k_pe1p(const u16* __restrict__ vt,
    const float* __restrict__ w, u16* __restrict__ gt)
{
  const int ch = blockIdx.y;
  const int y0 = blockIdx.x * 4;
  const int x = threadIdx.x;
  const u16* plane = vt + (size_t)ch * 65536;
  float w9[9];
#pragma unroll
  for (int k = 0; k < 9; k++) w9[k] = w[ch * 9 + k];   // uniform -> sgpr
#pragma unroll
  for (int ry = 0; ry < 4; ry++) {
    int y = y0 + ry;
    float s = 0.f;
#pragma unroll
    for (int ky = 0; ky < 3; ky++) {
      int yy = y + ky - 1;
      if ((unsigned)yy < 256u) {
#pragma unroll
        for (int kx = 0; kx < 3; kx++) {
          int xx = x + kx - 1;
          if ((unsigned)xx < 256u)
            s += w9[ky * 3 + kx] * bf2f(plane[yy * 256 + xx]);
        }
      }
    }
    float gl = 0.5f * s * (1.f + erff(s * 0.70710678118654752f));
    gt[(size_t)ch * 65536 + y * 256 + x] = f2bf(gl);
  }
}

// ---------------- pe2: depthwise3x3 on GT plane, transposed add into out[n][c] ----------------
__global__ __launch_bounds__(256) void k_pe2p(const u16* __restrict__ gt,
    const float* __restrict__ w, float* __restrict__ out)
{
  __shared__ float tile[64][65];
  const int t = blockIdx.x;                // 0..1023: y = t>>2, x-chunk = t&3
  const int y = t >> 2, x0 = (t & 3) * 64;
  const int cg = blockIdx.y * 64;
  const int wv = threadIdx.x >> 6, lane = threadIdx.x & 63;
  const int x = x0 + lane;
  for (int i = 0; i < 16; i++) {
    int c = cg + wv * 16 + i;               // wave-uniform channel
    const u16* plane = gt + (size_t)c * 65536;
    float s = 0.f;
#pragma unroll
    for (int ky = 0; ky < 3; ky++) {
      int yy = y + ky - 1;
      if ((unsigned)yy < 256u) {
#pragma unroll
        for (int kx = 0; kx < 3; kx++) {
          int xx = x + kx - 1;
          if ((unsigned)xx < 256u)
            s += w[c * 9 + ky * 3 + kx] * bf2f(plane[yy * 256 + xx]);
        }
      }
    }
    tile[wv * 16 + i][lane] = s;
  }
  __syncthreads();
#pragma unroll
  for (int k = 0; k < 4; k++) {
    int idx = k * 256 + threadIdx.x;
    int c4 = idx & 15, pl = idx >> 4;
    float4 add = make_float4(tile[c4 * 4 + 0][pl], tile[c4 * 4 + 1][pl],
                             tile[c4 * 4 + 2][pl], tile[c4 * 4 + 3][pl]);
    float* op = &out[(size_t)(y * 256 + x0 + pl) * 512 + cg + c4 * 4];
    float4 o = *(float4*)op;
    o.x += add.x; o.y += add.y; o.z += add.z; o.w += add.w;
    *(float4*)op = o;
  }
}

// =====================================================================
extern "C" void kernel_launch(void* const* d_in, const int* in_sizes, int n_in,
                              void* d_out, int out_size, void* d_ws, size_t ws_size,
                              hipStream_t stream)
{
  (void)in_sizes; (void)n_in; (void)out_size;
  const float* x    = (const float*)d_in[0];
  const float* sar  = (const float*)d_in[1];
  const float* Wq   = (const float*)d_in[2];
  const float* Wk   = (const float*)d_in[3];
  const float* Wv   = (const float*)d_in[4];
  const float* resc = (const float*)d_in[5];
  const float* Wp   = (const float*)d_in[6];
  const float* bp   = (const float*)d_in[7];
  const float* pe1w = (const float*)d_in[8];
  const float* pe2w = (const float*)d_in[9];
  const float* w3   = (const float*)d_in[10];
  const float* b3   = (const float*)d_in[11];
  const float* bng  = (const float*)d_in[12];
  const float* bnb  = (const float*)d_in[13];
  const float* sb   = (const float*)d_in[14];
  const float* w2c  = (const float*)d_in[15];
  const float* b2c  = (const float*)d_in[16];
  const float* w32  = (const float*)d_in[17];
  const float* b32  = (const float*)d_in[18];
  const float* dw   = (const float*)d_in[19];
  const float* db   = (const float*)d_in[20];
  float* out = (float*)d_out;

  if (ws_size < WS_NEEDED)
    fprintf(stderr, "MS_MSA: workspace too small: have %zu need %zu\n", ws_size, WS_NEEDED);

  char* ws = (char*)d_ws;
  u16* XB    = (u16*)(ws + OFF_XB);
  u16* XBT   = (u16*)(ws + OFF_XBT);
  u16* VB    = (u16*)(ws + OFF_VB);
  u16* VT    = (u16*)(ws + OFF_VT);
  float* GPART = (float*)(ws + OFF_GPART);
  float* G     = (float*)(ws + OFF_G);
  float* TQ    = (float*)(ws + OFF_TQ);
  float* TK    = (float*)(ws + OFF_TK);
  u16* WVT   = (u16*)(ws + OFF_WVT);
  u16* W2T   = (u16*)(ws + OFF_W2T);
  float* ASAR = (float*)(ws + OFF_ASAR);
  float* SS   = (float*)(ws + OFF_SS);
  float* BNP  = (float*)(ws + OFF_BNP);
  float* QN   = (float*)(ws + OFF_QN);
  float* KN   = (float*)(ws + OFF_KN);
  float* ATTN = (float*)(ws + OFF_ATTN);
  u16* VMT = XB;    // alias: XB dead after gemm_v
  u16* GT  = XBT;   // alias: XBT dead after Gram
  u16* VM  = VB;    // alias: VB dead after k_tbf16 (VB->VT)

  // --- x -> bf16 (row + transposed) ---
  k_cast_transpose<<<dim3(1024, 8), 256, 0, stream>>>(x, XB, XBT);
  // --- G = X^T X ---
  gemm_bt<1><<<dim3(4, 4, GSPLIT), 256, 0, stream>>>(XBT, NTOK, XBT, NTOK, GKLEN, GPART, nullptr);
  k_reduce_g<<<1024, 256, 0, stream>>>(GPART, G);
  // --- v_inp = x @ Wv ---
  k_transpose_w<<<dim3(8, 8), 256, 0, stream>>>(Wv, WVT);
  gemm_bt<0><<<dim3(512, 4), 256, 0, stream>>>(XB, 512, WVT, 512, 512, VB, nullptr);
  k_tbf16<<<dim3(1024, 8), 256, 0, stream>>>(VB, VT, 65536, 512);
  // --- attention stats ---
  k_gw<<<dim3(8, 8, 2), 256, 0, stream>>>(G, Wq, Wk, TQ, TK);
  k_norms<<<256, 256, 0, stream>>>(Wq, TQ, Wk, TK, QN, KN);
  k_attn<<<8, 256, 0, stream>>>(Wk, TQ, QN, KN, resc, ATTN);
  k_w2t<<<64, 256, 0, stream>>>(ATTN, Wp, W2T);
  // --- SAR branch ---
  k_conv3<<<dim3(256, 2), 256, 0, stream>>>(sar, w3, b3, ASAR);
  k_bnstats<<<2, 256, 0, stream>>>(ASAR, bng, bnb, BNP);
  k_sar2<<<256, 256, 0, stream>>>(ASAR, BNP, sb, SS);
  // --- mask + gate (plane layout) ---
  k_mask2<<<dim3(64, 128), 256, 0, stream>>>(SS, w2c, b2c, w32, b32, dw, db, VT, VMT);
  k_tbf16<<<dim3(8, 1024), 256, 0, stream>>>(VMT, VM, 512, 65536);
  // --- out = vm @ W2 + bp ---
  gemm_bt<2><<<dim3(512, 4), 256, 0, stream>>>(VM, 512, W2T, 512, 512, out, bp);
  // --- positional branch ---
  k_pe1p<<<dim3(64, 512), 256, 0, stream>>>(VT, pe1w, GT);
  k_pe2p<<<dim3(1024, 8), 256, 0, stream>>>(GT, pe2w, out);
}

// Round 3
// 974.329 us; speedup vs baseline: 3.2632x; 1.2440x over previous
//
#include <hip/hip_runtime.h>
#include <cstdint>
#include <cstdio>

typedef unsigned short u16;
typedef __attribute__((ext_vector_type(8))) short short8;   // 8 bf16 (4 VGPRs)
typedef __attribute__((ext_vector_type(4))) float f32x4;

#define DEVFN __device__ __forceinline__

DEVFN u16 f2bf(float f){ union{float f; unsigned u;} v; v.f=f; unsigned r = v.u + 0x7fffu + ((v.u>>16)&1u); return (u16)(r>>16); }
DEVFN float bf2f(u16 h){ union{unsigned u; float f;} v; v.u = ((unsigned)h)<<16; return v.f; }

// async global->LDS, 16B per lane (dwordx4). LDS dest must be wave-uniform base + lane*16.
#define GLOAD_LDS16(gp, lp) __builtin_amdgcn_global_load_lds( \
    (const __attribute__((address_space(1))) void*)(gp), \
    (__attribute__((address_space(3))) void*)(lp), 16, 0, 0)

// ---------------- problem constants ----------------
static constexpr int NTOK = 65536;   // H*W
static constexpr int GSPLIT = 32;    // split-K slabs for Gram
static constexpr int GKLEN  = NTOK / GSPLIT;

// ---------------- workspace layout (bytes) ----------------
static constexpr size_t MB = 1024 * 1024;
static constexpr size_t OFF_XB    = 0;          // bf16 x  [n][c]    64 MiB   (alias: VMT)
static constexpr size_t OFF_XBT   = 64 * MB;    // bf16 x^T [c][n]   64 MiB   (alias: GT)
static constexpr size_t OFF_VB    = 128 * MB;   // bf16 v_inp [n][c] 64 MiB   (alias: VM)
static constexpr size_t OFF_VT    = 192 * MB;   // bf16 v^T [c][n]   64 MiB
static constexpr size_t OFF_GPART = 256 * MB;   // fp32 [32][512][512] 32 MiB
static constexpr size_t OFF_G     = 288 * MB;
static constexpr size_t OFF_TQ    = 289 * MB;
static constexpr size_t OFF_TK    = 290 * MB;
static constexpr size_t OFF_WVT   = 291 * MB;            // bf16 Wv^T
static constexpr size_t OFF_W2T   = 291 * MB + 524288;   // bf16 W2^T
static constexpr size_t OFF_ASAR  = 292 * MB;            // fp32 [2][65536]
static constexpr size_t OFF_SS    = 292 * MB + 524288;   // fp32 [2][65536]
static constexpr size_t OFF_BNP   = 293 * MB;
static constexpr size_t OFF_QN    = 293 * MB + 4096;
static constexpr size_t OFF_KN    = 293 * MB + 8192;
static constexpr size_t OFF_ATTN  = 293 * MB + 12288;    // fp32 [8][64][64]
static constexpr size_t WS_NEEDED = 294 * MB;

// =====================================================================
// bf16 MFMA GEMM: C[M][512] = A[M][K] * B with B stored as [N][K] (B^T).
// 128x128 tile, 4 waves 2x2, wave = 64x64 via 4x4 16x16x32 frags.
// Staging via global_load_lds width=16 (m97 pattern).
// MODE 0: bf16 C. MODE 1: fp32 partial slab (split-K, z). MODE 2: fp32 C + bias.
// =====================================================================
template<int MODE>
__global__ __launch_bounds__(256) void gemm_bt(
    const u16* __restrict__ A, int lda,
    const u16* __restrict__ B, int ldb,
    int klen,
    void* __restrict__ Cout,
    const float* __restrict__ bias)
{
  __shared__ uint4 smem[1024];  // A tile [0..511] = 128x32 bf16 (64B rows); B tile [512..1023]
  const int tid  = threadIdx.x;
  const int lane = tid & 63;
  const int wv   = tid >> 6;
  const int wm   = (wv >> 1) * 64;
  const int wn   = (wv & 1) * 64;
  const int m0   = blockIdx.x * 128;
  const int n0   = blockIdx.y * 128;
  const int kb   = blockIdx.z * klen;

  const int q0 = tid, q1 = tid + 256;
  const size_t arow0 = (size_t)(m0 + (q0 >> 2)) * lda + (q0 & 3) * 8;
  const size_t arow1 = (size_t)(m0 + (q1 >> 2)) * lda + (q1 & 3) * 8;
  const size_t brow0 = (size_t)(n0 + (q0 >> 2)) * ldb + (q0 & 3) * 8;
  const size_t brow1 = (size_t)(n0 + (q1 >> 2)) * ldb + (q1 & 3) * 8;

  f32x4 acc[4][4] = {};
  const char* lAc = (const char*)smem;
  const char* lBc = (const char*)(smem + 512);
  const int ko = (lane >> 4) * 16;
  const int ma = lane & 15;

  for (int k0 = kb; k0 < kb + klen; k0 += 32) {
    __syncthreads();                      // all waves done reading previous tile
    GLOAD_LDS16(&A[arow0 + k0], &smem[q0]);
    GLOAD_LDS16(&A[arow1 + k0], &smem[q1]);
    GLOAD_LDS16(&B[brow0 + k0], &smem[512 + q0]);
    GLOAD_LDS16(&B[brow1 + k0], &smem[512 + q1]);
    __syncthreads();                      // drains vmcnt -> LDS data visible
    short8 af[4], bfr[4];
#pragma unroll
    for (int mt = 0; mt < 4; mt++)
      af[mt] = *(const short8*)(lAc + (wm + mt * 16 + ma) * 64 + ko);
#pragma unroll
    for (int nt = 0; nt < 4; nt++)
      bfr[nt] = *(const short8*)(lBc + (wn + nt * 16 + ma) * 64 + ko);
#pragma unroll
    for (int mt = 0; mt < 4; mt++)
#pragma unroll
      for (int nt = 0; nt < 4; nt++)
        acc[mt][nt] = __builtin_amdgcn_mfma_f32_16x16x32_bf16(af[mt], bfr[nt], acc[mt][nt], 0, 0, 0);
  }

  const int col = lane & 15;
  const int rq  = (lane >> 4) * 4;
  float* Cf = (float*)Cout;
  u16*   Ch = (u16*)Cout;
  if (MODE == 1) Cf += (size_t)blockIdx.z * 512 * 512;
#pragma unroll
  for (int mt = 0; mt < 4; mt++) {
#pragma unroll
    for (int nt = 0; nt < 4; nt++) {
      const int mbase = m0 + wm + mt * 16 + rq;
      const int nn    = n0 + wn + nt * 16 + col;
#pragma unroll
      for (int r = 0; r < 4; r++) {
        float vv = acc[mt][nt][r];
        size_t idx = (size_t)(mbase + r) * 512 + nn;
        if (MODE == 0)      Ch[idx] = f2bf(vv);
        else if (MODE == 1) Cf[idx] = vv;
        else                Cf[idx] = vv + bias[nn];
      }
    }
  }
}

// ---------------- x fp32 [n][512] -> bf16 xb [n][512] and xbT [512][n] ----------------
__global__ void k_cast_transpose(const float* __restrict__ x, u16* __restrict__ xb, u16* __restrict__ xbT)
{
  __shared__ u16 tile[64][72];
  const int t0 = blockIdx.x * 64, c0 = blockIdx.y * 64;
  const int tx = threadIdx.x & 15, ty = threadIdx.x >> 4;
#pragma unroll
  for (int p = 0; p < 4; p++) {
    int t = ty + p * 16;
    float4 v = *(const float4*)&x[(size_t)(t0 + t) * 512 + c0 + tx * 4];
    ushort4 u; u.x = f2bf(v.x); u.y = f2bf(v.y); u.z = f2bf(v.z); u.w = f2bf(v.w);
    *(ushort4*)&xb[(size_t)(t0 + t) * 512 + c0 + tx * 4] = u;
    tile[t][tx*4+0] = u.x; tile[t][tx*4+1] = u.y; tile[t][tx*4+2] = u.z; tile[t][tx*4+3] = u.w;
  }
  __syncthreads();
#pragma unroll
  for (int p = 0; p < 4; p++) {
    int c = ty + p * 16;
    ushort4 u;
    u.x = tile[tx*4+0][c]; u.y = tile[tx*4+1][c]; u.z = tile[tx*4+2][c]; u.w = tile[tx*4+3][c];
    *(ushort4*)&xbT[(size_t)(c0 + c) * 65536 + t0 + tx * 4] = u;
  }
}

// ---------------- generic bf16 tiled transpose: src[srows][scols] -> dst[scols][srows] ----------------
__global__ void k_tbf16(const u16* __restrict__ src, u16* __restrict__ dst, int srows, int scols)
{
  __shared__ u16 tile[64][72];
  const int r0 = blockIdx.x * 64, c0v = blockIdx.y * 64;
  const int tx = threadIdx.x & 15, ty = threadIdx.x >> 4;
#pragma unroll
  for (int p = 0; p < 4; p++) {
    int r = ty + p * 16;
    ushort4 u = *(const ushort4*)&src[(size_t)(r0 + r) * scols + c0v + tx * 4];
    tile[r][tx*4+0] = u.x; tile[r][tx*4+1] = u.y; tile[r][tx*4+2] = u.z; tile[r][tx*4+3] = u.w;
  }
  __syncthreads();
#pragma unroll
  for (int p = 0; p < 4; p++) {
    int c = ty + p * 16;
    ushort4 u;
    u.x = tile[tx*4+0][c]; u.y = tile[tx*4+1][c]; u.z = tile[tx*4+2][c]; u.w = tile[tx*4+3][c];
    *(ushort4*)&dst[(size_t)(c0v + c) * srows + r0 + tx * 4] = u;
  }
}

// ---------------- W fp32 [512][512] -> bf16 W^T ----------------
__global__ void k_transpose_w(const float* __restrict__ Wsrc, u16* __restrict__ WT)
{
  __shared__ u16 tile[64][72];
  const int k0 = blockIdx.x * 64, n0 = blockIdx.y * 64;
  const int tx = threadIdx.x & 15, ty = threadIdx.x >> 4;
#pragma unroll
  for (int p = 0; p < 4; p++) {
    int t = ty + p * 16;
    float4 v = *(const float4*)&Wsrc[(size_t)(k0 + t) * 512 + n0 + tx * 4];
    tile[t][tx*4+0] = f2bf(v.x); tile[t][tx*4+1] = f2bf(v.y);
    tile[t][tx*4+2] = f2bf(v.z); tile[t][tx*4+3] = f2bf(v.w);
  }
  __syncthreads();
#pragma unroll
  for (int p = 0; p < 4; p++) {
    int c = ty + p * 16;
    ushort4 u;
    u.x = tile[tx*4+0][c]; u.y = tile[tx*4+1][c]; u.z = tile[tx*4+2][c]; u.w = tile[tx*4+3][c];
    *(ushort4*)&WT[(size_t)(n0 + c) * 512 + k0 + tx * 4] = u;
  }
}

// ---------------- reduce Gram partials ----------------
__global__ void k_reduce_g(const float* __restrict__ part, float* __restrict__ G)
{
  const int i = blockIdx.x * 256 + threadIdx.x;
  float s = 0.f;
  for (int z = 0; z < GSPLIT; z++) s += part[(size_t)z * 262144 + i];
  G[i] = s;
}

// ---------------- Tq = G@Wq, Tk = G@Wk ----------------
__global__ __launch_bounds__(256) void k_gw(const float* __restrict__ G,
    const float* __restrict__ Wq, const float* __restrict__ Wk,
    float* __restrict__ Tq, float* __restrict__ Tk)
{
  const float* Bm = blockIdx.z ? Wk : Wq;
  float* Cm = blockIdx.z ? Tk : Tq;
  __shared__ float As[64][68];
  __shared__ float Bs[64][68];
  const int i0 = blockIdx.x * 64, j0 = blockIdx.y * 64;
  const int tx = threadIdx.x & 15, ty = threadIdx.x >> 4;
  float acc[4][4] = {};
  for (int k0 = 0; k0 < 512; k0 += 64) {
    __syncthreads();
#pragma unroll
    for (int p = 0; p < 4; p++) {
      int r = ty + p * 16;
      float4 a = *(const float4*)&G [(size_t)(i0 + r) * 512 + k0 + tx * 4];
      float4 b = *(const float4*)&Bm[(size_t)(k0 + r) * 512 + j0 + tx * 4];
      *(float4*)&As[r][tx * 4] = a;
      *(float4*)&Bs[r][tx * 4] = b;
    }
    __syncthreads();
    for (int kk = 0; kk < 64; kk++) {
      float a0 = As[ty*4+0][kk], a1 = As[ty*4+1][kk], a2 = As[ty*4+2][kk], a3 = As[ty*4+3][kk];
      float4 bq = *(const float4*)&Bs[kk][tx * 4];
      acc[0][0] += a0*bq.x; acc[0][1] += a0*bq.y; acc[0][2] += a0*bq.z; acc[0][3] += a0*bq.w;
      acc[1][0] += a1*bq.x; acc[1][1] += a1*bq.y; acc[1][2] += a1*bq.z; acc[1][3] += a1*bq.w;
      acc[2][0] += a2*bq.x; acc[2][1] += a2*bq.y; acc[2][2] += a2*bq.z; acc[2][3] += a2*bq.w;
      acc[3][0] += a3*bq.x; acc[3][1] += a3*bq.y; acc[3][2] += a3*bq.z; acc[3][3] += a3*bq.w;
    }
  }
#pragma unroll
  for (int u = 0; u < 4; u++) {
    float4 o = make_float4(acc[u][0], acc[u][1], acc[u][2], acc[u][3]);
    *(float4*)&Cm[(size_t)(i0 + ty * 4 + u) * 512 + j0 + tx * 4] = o;
  }
}

// ---------------- norms ----------------
__global__ void k_norms(const float* __restrict__ Wq, const float* __restrict__ Tq,
                        const float* __restrict__ Wk, const float* __restrict__ Tk,
                        float* __restrict__ qn, float* __restrict__ kn)
{
  const int gw = (blockIdx.x * 256 + threadIdx.x) >> 6;
  const int lane = threadIdx.x & 63;
  const float* Wm = (gw < 512) ? Wq : Wk;
  const float* Tm = (gw < 512) ? Tq : Tk;
  const int c = gw & 511;
  float s = 0.f;
  for (int r = lane; r < 512; r += 64) s += Wm[(size_t)r * 512 + c] * Tm[(size_t)r * 512 + c];
  for (int off = 32; off > 0; off >>= 1) s += __shfl_down(s, off);
  if (lane == 0) {
    float n = sqrtf(fmaxf(s, 0.f));
    ((gw < 512) ? qn : kn)[c] = fmaxf(n, 1e-12f);
  }
}

// ---------------- per-head logits + softmax ----------------
__global__ __launch_bounds__(256) void k_attn(const float* __restrict__ Wk, const float* __restrict__ Tq,
    const float* __restrict__ qn, const float* __restrict__ kn,
    const float* __restrict__ rescale, float* __restrict__ attn)
{
  const int h = blockIdx.x, hd = h * 64;
  __shared__ float Ks[64][68];
  __shared__ float Qs[64][68];
  __shared__ float Ss[64][65];
  const int tx = threadIdx.x & 15, ty = threadIdx.x >> 4;
  float acc[4][4] = {};
  for (int k0 = 0; k0 < 512; k0 += 64) {
    __syncthreads();
#pragma unroll
    for (int p = 0; p < 4; p++) {
      int r = ty + p * 16;
      float4 a = *(const float4*)&Wk[(size_t)(k0 + r) * 512 + hd + tx * 4];
      float4 b = *(const float4*)&Tq[(size_t)(k0 + r) * 512 + hd + tx * 4];
      *(float4*)&Ks[r][tx * 4] = a;
      *(float4*)&Qs[r][tx * 4] = b;
    }
    __syncthreads();
    for (int kk = 0; kk < 64; kk++) {
      float a0 = Ks[kk][ty*4+0], a1 = Ks[kk][ty*4+1], a2 = Ks[kk][ty*4+2], a3 = Ks[kk][ty*4+3];
      float4 bq = *(const float4*)&Qs[kk][tx * 4];
      acc[0][0] += a0*bq.x; acc[0][1] += a0*bq.y; acc[0][2] += a0*bq.z; acc[0][3] += a0*bq.w;
      acc[1][0] += a1*bq.x; acc[1][1] += a1*bq.y; acc[1][2] += a1*bq.z; acc[1][3] += a1*bq.w;
      acc[2][0] += a2*bq.x; acc[2][1] += a2*bq.y; acc[2][2] += a2*bq.z; acc[2][3] += a2*bq.w;
      acc[3][0] += a3*bq.x; acc[3][1] += a3*bq.y; acc[3][2] += a3*bq.z; acc[3][3] += a3*bq.w;
    }
  }
#pragma unroll
  for (int u = 0; u < 4; u++)
#pragma unroll
    for (int v = 0; v < 4; v++)
      Ss[ty * 4 + u][tx * 4 + v] = acc[u][v];
  __syncthreads();
  if (threadIdx.x < 64) {
    const int i = threadIdx.x;
    const float sci = rescale[h] / kn[hd + i];
    float mx = -1e30f;
    for (int j = 0; j < 64; j++) {
      float L = Ss[i][j] * sci / qn[hd + j];
      Ss[i][j] = L;
      mx = fmaxf(mx, L);
    }
    float sum = 0.f;
    for (int j = 0; j < 64; j++) { float e = __expf(Ss[i][j] - mx); Ss[i][j] = e; sum += e; }
    float inv = 1.f / sum;
    for (int j = 0; j < 64; j++) attn[(size_t)h * 4096 + i * 64 + j] = Ss[i][j] * inv;
  }
}

// ---------------- fold attn into Wp ----------------
__global__ void k_w2t(const float* __restrict__ attn, const float* __restrict__ Wp, u16* __restrict__ W2T)
{
  const int h = blockIdx.x >> 3, e0 = (blockIdx.x & 7) * 64;
  __shared__ float As[64][65];
  for (int p = 0; p < 16; p++) {
    int idx = p * 256 + threadIdx.x;
    As[idx >> 6][idx & 63] = attn[(size_t)h * 4096 + idx];
  }
  __syncthreads();
  const int e = e0 + (threadIdx.x & 63);
  const int j4 = threadIdx.x >> 6;
  float s[16];
#pragma unroll
  for (int jj = 0; jj < 16; jj++) s[jj] = 0.f;
  for (int i = 0; i < 64; i++) {
    float wv_ = Wp[(size_t)(h * 64 + i) * 512 + e];
#pragma unroll
    for (int jj = 0; jj < 16; jj++) s[jj] += As[i][j4 * 16 + jj] * wv_;
  }
#pragma unroll
  for (int jj = 0; jj < 16; jj++)
    W2T[(size_t)e * 512 + h * 64 + j4 * 16 + jj] = f2bf(s[jj]);
}

// ---------------- SAR branch ----------------
__global__ void k_conv3(const float* __restrict__ sar, const float* __restrict__ w3,
                        const float* __restrict__ b3, float* __restrict__ a)
{
  const int oc = blockIdx.y;
  const int p = blockIdx.x * 256 + threadIdx.x;
  const int y = p >> 8, x = p & 255;
  float s = b3[oc];
#pragma unroll
  for (int ic = 0; ic < 2; ic++) {
    const float* img = sar + ic * 65536;
    const float* w = w3 + oc * 18 + ic * 9;
#pragma unroll
    for (int k = 0; k < 9; k++) {
      int yy = y + k / 3 - 1, xx = x + k % 3 - 1;
      if ((unsigned)yy < 256u && (unsigned)xx < 256u) s += w[k] * img[yy * 256 + xx];
    }
  }
  a[oc * 65536 + p] = s;
}

__global__ void k_bnstats(const float* __restrict__ a, const float* __restrict__ g,
                          const float* __restrict__ b, float* __restrict__ bnp)
{
  const int ch = blockIdx.x;
  const int tid = threadIdx.x;
  const float* src = a + ch * 65536;
  float s = 0.f, sq = 0.f;
  for (int i = tid; i < 65536; i += 256) { float v = src[i]; s += v; sq += v * v; }
  __shared__ float rs[256], rq[256];
  rs[tid] = s; rq[tid] = sq;
  __syncthreads();
  for (int o = 128; o > 0; o >>= 1) {
    if (tid < o) { rs[tid] += rs[tid + o]; rq[tid] += rq[tid + o]; }
    __syncthreads();
  }
  if (tid == 0) {
    float mu = rs[0] * (1.f / 65536.f);
    float var = rq[0] * (1.f / 65536.f) - mu * mu;
    float scale = g[ch] / sqrtf(var + 1e-5f);
    bnp[ch] = scale;
    bnp[2 + ch] = b[ch] - mu * scale;
  }
}

__global__ void k_sar2(const float* __restrict__ a, const float* __restrict__ bnp,
                       const float* __restrict__ sb, float* __restrict__ ss)
{
  const int p = blockIdx.x * 256 + threadIdx.x;
  const int y = p >> 8, x = p & 255;
  const float sc0 = bnp[0], sc1 = bnp[1], sh0 = bnp[2], sh1 = bnp[3];
  float bs[9];
  float bn0c = 0.f, bn1c = 0.f;
#pragma unroll
  for (int k = 0; k < 9; k++) {
    int yy = y + k / 3 - 1, xx = x + k % 3 - 1;
    float v0 = 0.f, v1 = 0.f;
    if ((unsigned)yy < 256u && (unsigned)xx < 256u) {
      int q = yy * 256 + xx;
      v0 = a[q] * sc0 + sh0;
      v1 = a[65536 + q] * sc1 + sh1;
    }
    bs[k] = v0 + v1;
    if (k == 4) { bn0c = v0; bn1c = v1; }
  }
  float gv = (bs[6] + 2.f * bs[7] + bs[8]) - (bs[0] + 2.f * bs[1] + bs[2]);
  float gh = (bs[2] + 2.f * bs[5] + bs[8]) - (bs[0] + 2.f * bs[3] + bs[6]);
  float s0 = gv + sb[0], s1 = gh + sb[1], s2 = gv + sb[2], s3 = gh + sb[3];
  ss[p]         = sqrtf(s0 * s0 + s1 * s1) + bn0c;
  ss[65536 + p] = sqrtf(s2 * s2 + s3 * s3) + bn1c;
}

// =====================================================================
// k_mask2: mask = e1 + sigmoid(conv32(s)) + depthwise5x5(e1), vmt = vt * mask.
// Plane layout: block = 32x32 pixel tile x channel-quad (blockIdx.y).
// e1 = a*s0 + b*s1 + beta*iota  (rank-2 + indicator) -> dconv via u0,u1,ui.
// =====================================================================
__global__ __launch_bounds__(256) void k_mask2(
    const float* __restrict__ ss,
    const float* __restrict__ w2,  const float* __restrict__ b2,
    const float* __restrict__ w32, const float* __restrict__ b32,
    const float* __restrict__ dw,  const float* __restrict__ db,
    const u16* __restrict__ vt, u16* __restrict__ vmt)
{
  __shared__ __align__(16) float sw0[1296];  // 36x36 window of s0 (zero-padded)
  __shared__ __align__(16) float sw1[1296];
  __shared__ __align__(16) float swi[1296];  // in-bounds indicator
  const int bxx = blockIdx.x & 7, byy = blockIdx.x >> 3;
  const int tx0 = bxx * 32, ty0 = byy * 32;
  const int c0 = blockIdx.y * 4;
  const bool border = (bxx == 0) || (bxx == 7) || (byy == 0) || (byy == 7);

  for (int i = threadIdx.x; i < 1296; i += 256) {
    int r = i / 36, cl = i - r * 36;
    int gy = ty0 - 2 + r, gx = tx0 - 2 + cl;
    bool in = ((unsigned)gy < 256u) & ((unsigned)gx < 256u);
    int gp = gy * 256 + gx;
    sw0[i] = in ? ss[gp] : 0.f;
    sw1[i] = in ? ss[65536 + gp] : 0.f;
    swi[i] = in ? 1.f : 0.f;
  }
  __syncthreads();

  const int g = threadIdx.x & 7;      // x-group: 4 px each
  const int row = threadIdx.x >> 3;   // 0..31
  float u0[4][4] = {}, u1[4][4] = {}, ui[4][4] = {}, a32[4][4] = {};
  float s0c[4], s1c[4];

#pragma unroll
  for (int ky = 0; ky < 5; ky++) {
    const float* rp0 = &sw0[(row + ky) * 36 + g * 4];
    const float* rp1 = &sw1[(row + ky) * 36 + g * 4];
    float4 p0a = *(const float4*)rp0, p0b = *(const float4*)(rp0 + 4);
    float4 p1a = *(const float4*)rp1, p1b = *(const float4*)(rp1 + 4);
    float r0[8] = {p0a.x, p0a.y, p0a.z, p0a.w, p0b.x, p0b.y, p0b.z, p0b.w};
    float r1[8] = {p1a.x, p1a.y, p1a.z, p1a.w, p1b.x, p1b.y, p1b.z, p1b.w};
    if (ky == 2) {
#pragma unroll
      for (int j = 0; j < 4; j++) { s0c[j] = r0[j + 2]; s1c[j] = r1[j + 2]; }
    }
#pragma unroll
    for (int dx = 0; dx < 5; dx++) {
#pragma unroll
      for (int cc = 0; cc < 4; cc++) {
        float wdw = dw[(c0 + cc) * 25 + ky * 5 + dx];    // uniform -> s_load
#pragma unroll
        for (int j = 0; j < 4; j++) {
          u0[cc][j] += wdw * r0[dx + j];
          u1[cc][j] += wdw * r1[dx + j];
        }
      }
    }
    if (border) {
      const float* rpi = &swi[(row + ky) * 36 + g * 4];
      float4 pia = *(const float4*)rpi, pib = *(const float4*)(rpi + 4);
      float ri[8] = {pia.x, pia.y, pia.z, pia.w, pib.x, pib.y, pib.z, pib.w};
#pragma unroll
      for (int dx = 0; dx < 5; dx++)
#pragma unroll
        for (int cc = 0; cc < 4; cc++) {
          float wdw = dw[(c0 + cc) * 25 + ky * 5 + dx];
#pragma unroll
          for (int j = 0; j < 4; j++) ui[cc][j] += wdw * ri[dx + j];
        }
    }
    if (ky >= 1 && ky <= 3) {
#pragma unroll
      for (int dx = 0; dx < 3; dx++)
#pragma unroll
        for (int cc = 0; cc < 4; cc++) {
          float wa = w32[(c0 + cc) * 18 + (ky - 1) * 3 + dx];
          float wb = w32[(c0 + cc) * 18 + 9 + (ky - 1) * 3 + dx];
#pragma unroll
          for (int j = 0; j < 4; j++)
            a32[cc][j] += wa * r0[dx + 1 + j] + wb * r1[dx + 1 + j];
        }
    }
  }

  const int y = ty0 + row, xg = tx0 + g * 4;
#pragma unroll
  for (int cc = 0; cc < 4; cc++) {
    const int c = c0 + cc;
    const float a = w2[c * 2], b = w2[c * 2 + 1], beta = b2[c];
    const float bb = b32[c], dbv = db[c];
    float wsum = 0.f;
    if (!border) {
#pragma unroll
      for (int t = 0; t < 25; t++) wsum += dw[c * 25 + t];
    }
    ushort4 vv = *(const ushort4*)&vt[(size_t)c * 65536 + y * 256 + xg];
    float vf[4] = {bf2f(vv.x), bf2f(vv.y), bf2f(vv.z), bf2f(vv.w)};
    ushort4 o;
    u16 ov[4];
#pragma unroll
    for (int j = 0; j < 4; j++) {
      float W = border ? ui[cc][j] : wsum;
      float sig = 1.f / (1.f + __expf(-(a32[cc][j] + bb)));
      float m = a * (s0c[j] + u0[cc][j]) + b * (s1c[j] + u1[cc][j])
              + beta * (1.f + W) + sig + dbv;
      ov[j] = f2bf(vf[j] * m);
    }
    o.x = ov[0]; o.y = ov[1]; o.z = ov[2]; o.w = ov[3];
    *(ushort4*)&vmt[(size_t)c * 65536 + y * 256 + xg] = o;
  }
}

// =====================================================================
// Vectorized depthwise 3x3 (plane layout). Wave = 16 x-subgroups x 4 channels;
// lane loads ushort4 per row, halo via shfl; edge subgroups do predicated u16 load.
// Block: y-row (blockIdx.x>>2), 64-px x-chunk (blockIdx.x&3), 64-ch group (blockIdx.y).
// =====================================================================
DEVFN void dw3x3_row4(const u16* plane, int y, int x0, int sub,
                      const float* w9, float& s0, float& s1, float& s2, float& s3)
{
#pragma unroll
  for (int r = 0; r < 3; r++) {
    int yy = y + r - 1;
    if ((unsigned)yy < 256u) {       // block-uniform branch
      const int base = yy * 256 + x0 + sub * 4;
      ushort4 p = *(const ushort4*)&plane[base];
      float v0 = bf2f(p.x), v1 = bf2f(p.y), v2 = bf2f(p.z), v3 = bf2f(p.w);
      float lf = __shfl_up(v3, 1);
      float rt = __shfl_down(v0, 1);
      if (sub == 0)  lf = (x0 > 0)   ? bf2f(plane[yy * 256 + x0 - 1])  : 0.f;
      if (sub == 15) rt = (x0 < 192) ? bf2f(plane[yy * 256 + x0 + 64]) : 0.f;
      const float wa = w9[r * 3], wb = w9[r * 3 + 1], wc = w9[r * 3 + 2];
      s0 += wa * lf + wb * v0 + wc * v1;
      s1 += wa * v0 + wb * v1 + wc * v2;
      s2 += wa * v1 + wb * v2 + wc * v3;
      s3 += wa * v2 + wb * v3 + wc * rt;
    }
  }
}

// pe1: dconv3x3(VT) -> exact GELU -> GT (plane layout, vectorized)
__global__ __launch_bounds__(256) void k_pe1v(const u16* __restrict__ vt,
    const float* __restrict__ w, u16* __restrict__ gt)
{
  const int t = blockIdx.x;
  const int y = t >> 2, x0 = (t & 3) * 64;
  const int cg = blockIdx.y * 64;
  const int lane = threadIdx.x & 63, wvq = threadIdx.x >> 6;
  const int sub = lane & 15, chq = lane >> 4;
#pragma unroll
  for (int i = 0; i < 4; i++) {
    const int c = cg + wvq * 16 + i * 4 + chq;
    const u16* plane = vt + (size_t)c * 65536;
    float w9[9];
#pragma unroll
    for (int k = 0; k < 9; k++) w9[k] = w[c * 9 + k];
    float s0 = 0.f, s1 = 0.f, s2 = 0.f, s3 = 0.f;
    dw3x3_row4(plane, y, x0, sub, w9, s0, s1, s2, s3);
    const float ksc = 0.70710678118654752f;
    s0 = 0.5f * s0 * (1.f + erff(s0 * ksc));
    s1 = 0.5f * s1 * (1.f + erff(s1 * ksc));
    s2 = 0.5f * s2 * (1.f + erff(s2 * ksc));
    s3 = 0.5f * s3 * (1.f + erff(s3 * ksc));
    ushort4 o; o.x = f2bf(s0); o.y = f2bf(s1); o.z = f2bf(s2); o.w = f2bf(s3);
    *(ushort4*)&gt[(size_t)c * 65536 + y * 256 + x0 + sub * 4] = o;
  }
}

// pe2: dconv3x3(GT), LDS transpose (conflict-free), float4 RMW add into out[n][c]
__global__ __launch_bounds__(256) void k_pe2v(const u16* __restrict__ gt,
    const float* __restrict__ w, float* __restrict__ out)
{
  __shared__ float tile[64][65];   // [ch][px]: writes bank=(ch+4*sub)%32 -> 2-way max
  const int t = blockIdx.x;
  const int y = t >> 2, x0 = (t & 3) * 64;
  const int cg = blockIdx.y * 64;
  const int lane = threadIdx.x & 63, wvq = threadIdx.x >> 6;
  const int sub = lane & 15, chq = lane >> 4;
#pragma unroll
  for (int i = 0; i < 4; i++) {
    const int cl = wvq * 16 + i * 4 + chq;
    const int c = cg + cl;
    const u16* plane = gt + (size_t)c * 65536;
    float w9[9];
#pragma unroll
    for (int k = 0; k < 9; k++) w9[k] = w[c * 9 + k];
    float s0 = 0.f, s1 = 0.f, s2 = 0.f, s3 = 0.f;
    dw3x3_row4(plane, y, x0, sub, w9, s0, s1, s2, s3);
    tile[cl][sub * 4 + 0] = s0;
    tile[cl][sub * 4 + 1] = s1;
    tile[cl][sub * 4 + 2] = s2;
    tile[cl][sub * 4 + 3] = s3;
  }
  __syncthreads();
#pragma unroll
  for (int k = 0; k < 4; k++) {
    const int idx = k * 256 + threadIdx.x;
    const int q = idx & 15, pl = idx >> 4;
    float4 add = make_float4(tile[q * 4 + 0][pl], tile[q * 4 + 1][pl],
                             tile[q * 4 + 2][pl], tile[q * 4 + 3][pl]);
    float* op = &out[(size_t)(y * 256 + x0 + pl) * 512 + cg + q * 4];
    float4 o = *(float4*)op;
    o.x += add.x; o.y += add.y; o.z += add.z; o.w += add.w;
    *(float4*)op = o;
  }
}

// =====================================================================
extern "C" void kernel_launch(void* const* d_in, const int* in_sizes, int n_in,
                              void* d_out, int out_size, void* d_ws, size_t ws_size,
                              hipStream_t stream)
{
  (void)in_sizes; (void)n_in; (void)out_size;
  const float* x    = (const float*)d_in[0];
  const float* sar  = (const float*)d_in[1];
  const float* Wq   = (const float*)d_in[2];
  const float* Wk   = (const float*)d_in[3];
  const float* Wv   = (const float*)d_in[4];
  const float* resc = (const float*)d_in[5];
  const float* Wp   = (const float*)d_in[6];
  const float* bp   = (const float*)d_in[7];
  const float* pe1w = (const float*)d_in[8];
  const float* pe2w = (const float*)d_in[9];
  const float* w3   = (const float*)d_in[10];
  const float* b3   = (const float*)d_in[11];
  const float* bng  = (const float*)d_in[12];
  const float* bnb  = (const float*)d_in[13];
  const float* sb   = (const float*)d_in[14];
  const float* w2c  = (const float*)d_in[15];
  const float* b2c  = (const float*)d_in[16];
  const float* w32  = (const float*)d_in[17];
  const float* b32  = (const float*)d_in[18];
  const float* dw   = (const float*)d_in[19];
  const float* db   = (const float*)d_in[20];
  float* out = (float*)d_out;

  if (ws_size < WS_NEEDED)
    fprintf(stderr, "MS_MSA: workspace too small: have %zu need %zu\n", ws_size, WS_NEEDED);

  char* ws = (char*)d_ws;
  u16* XB    = (u16*)(ws + OFF_XB);
  u16* XBT   = (u16*)(ws + OFF_XBT);
  u16* VB    = (u16*)(ws + OFF_VB);
  u16* VT    = (u16*)(ws + OFF_VT);
  float* GPART = (float*)(ws + OFF_GPART);
  float* G     = (float*)(ws + OFF_G);
  float* TQ    = (float*)(ws + OFF_TQ);
  float* TK    = (float*)(ws + OFF_TK);
  u16* WVT   = (u16*)(ws + OFF_WVT);
  u16* W2T   = (u16*)(ws + OFF_W2T);
  float* ASAR = (float*)(ws + OFF_ASAR);
  float* SS   = (float*)(ws + OFF_SS);
  float* BNP  = (float*)(ws + OFF_BNP);
  float* QN   = (float*)(ws + OFF_QN);
  float* KN   = (float*)(ws + OFF_KN);
  float* ATTN = (float*)(ws + OFF_ATTN);
  u16* VMT = XB;    // alias: XB dead after gemm_v
  u16* GT  = XBT;   // alias: XBT dead after Gram
  u16* VM  = VB;    // alias: VB dead after k_tbf16 (VB->VT)

  // --- x -> bf16 (row + transposed) ---
  k_cast_transpose<<<dim3(1024, 8), 256, 0, stream>>>(x, XB, XBT);
  // --- G = X^T X ---
  gemm_bt<1><<<dim3(4, 4, GSPLIT), 256, 0, stream>>>(XBT, NTOK, XBT, NTOK, GKLEN, GPART, nullptr);
  k_reduce_g<<<1024, 256, 0, stream>>>(GPART, G);
  // --- v_inp = x @ Wv ---
  k_transpose_w<<<dim3(8, 8), 256, 0, stream>>>(Wv, WVT);
  gemm_bt<0><<<dim3(512, 4), 256, 0, stream>>>(XB, 512, WVT, 512, 512, VB, nullptr);
  k_tbf16<<<dim3(1024, 8), 256, 0, stream>>>(VB, VT, 65536, 512);
  // --- attention stats ---
  k_gw<<<dim3(8, 8, 2), 256, 0, stream>>>(G, Wq, Wk, TQ, TK);
  k_norms<<<256, 256, 0, stream>>>(Wq, TQ, Wk, TK, QN, KN);
  k_attn<<<8, 256, 0, stream>>>(Wk, TQ, QN, KN, resc, ATTN);
  k_w2t<<<64, 256, 0, stream>>>(ATTN, Wp, W2T);
  // --- SAR branch ---
  k_conv3<<<dim3(256, 2), 256, 0, stream>>>(sar, w3, b3, ASAR);
  k_bnstats<<<2, 256, 0, stream>>>(ASAR, bng, bnb, BNP);
  k_sar2<<<256, 256, 0, stream>>>(ASAR, BNP, sb, SS);
  // --- mask + gate (plane layout) ---
  k_mask2<<<dim3(64, 128), 256, 0, stream>>>(SS, w2c, b2c, w32, b32, dw, db, VT, VMT);
  k_tbf16<<<dim3(8, 1024), 256, 0, stream>>>(VMT, VM, 512, 65536);
  // --- out = vm @ W2 + bp ---
  gemm_bt<2><<<dim3(512, 4), 256, 0, stream>>>(VM, 512, W2T, 512, 512, out, bp);
  // --- positional branch (vectorized) ---
  k_pe1v<<<dim3(1024, 8), 256, 0, stream>>>(VT, pe1w, GT);
  k_pe2v<<<dim3(1024, 8), 256, 0, stream>>>(GT, pe2w, out);
}